// Round 3
// baseline (188.652 us; speedup 1.0000x reference)
//
#include <hip/hip_runtime.h>

// EncoderBlock on MI355X. Round 17: ffn_fused gets counted-vmcnt double
// buffering (T4): raw s_barrier + "s_waitcnt vmcnt(4)" instead of
// __syncthreads' implicit vmcnt(0) drain, 2-tile-deep B prefetch that stays
// in flight across barriers. Only reaches vmcnt(0) at the last tile.
// Everything else identical to r16 (183.6 µs). B=16 T=1024 C=256 H=8 D=32.

typedef unsigned short u16;
typedef unsigned int u32;
typedef __attribute__((ext_vector_type(8))) short short8v;  // 8 bf16 MFMA A/B frag
typedef __attribute__((ext_vector_type(4))) float float4v;  // MFMA C/D frag

__device__ __forceinline__ float b2f(u16 u) { union { u32 i; float f; } v; v.i = (u32)u << 16; return v.f; }
__device__ __forceinline__ float lo2f(u32 u) { union { u32 i; float f; } v; v.i = u << 16; return v.f; }
__device__ __forceinline__ float hi2f(u32 u) { union { u32 i; float f; } v; v.i = u & 0xffff0000u; return v.f; }
__device__ __forceinline__ u16 f2b(float f) {
    union { float f; u32 i; } v; v.f = f;
    u32 r = v.i + 0x7fffu + ((v.i >> 16) & 1u);  // RTNE
    return (u16)(r >> 16);
}
__device__ __forceinline__ u32 pk2_rtz(float a, float b) {
    return (__float_as_uint(a) >> 16) | (__float_as_uint(b) & 0xffff0000u);
}
__device__ __forceinline__ void async_cp16(const u16* g, u16* l) {
    __builtin_amdgcn_global_load_lds((const __attribute__((address_space(1))) void*)g,
                                     (__attribute__((address_space(3))) void*)l, 16, 0, 0);
}

// ---------------- fused prep (wqkv pack + 3 transposes) + LN1 ---------------
__global__ __launch_bounds__(256) void prep_ln1(const float* __restrict__ wq,
                                                const float* __restrict__ wk,
                                                const float* __restrict__ wv,
                                                const float* __restrict__ wp,
                                                const float* __restrict__ w1,
                                                const float* __restrict__ w2,
                                                const float* __restrict__ x,
                                                const float* __restrict__ g1,
                                                const float* __restrict__ be1,
                                                u16* __restrict__ wqkvT,
                                                u16* __restrict__ wpT,
                                                u16* __restrict__ w1T,
                                                u16* __restrict__ w2T,
                                                u16* __restrict__ hout) {
    __shared__ u16 tile[64][65];
    int bid = blockIdx.x, tid = threadIdx.x;
    if (bid < 768) {
        int i = bid * 256 + tid;
        int n = i >> 8, k = i & 255;
        int which = n >> 8, nn = n & 255;
        const float* w = which == 0 ? wq : (which == 1 ? wk : wv);
        float v = w[((nn >> 5) * 256 + k) * 32 + (nn & 31)];   // w[h][k][d]
        if (which == 0) v *= 0.09016844f;                      // (1/16)*log2(e)
        wqkvT[i] = f2b(v);
    } else if (bid < 912) {
        const float* src; u16* dst; int K, N, t;
        if (bid < 784)      { src = wp; dst = wpT; K = 256;  N = 256;  t = bid - 768; }
        else if (bid < 848) { src = w1; dst = w1T; K = 256;  N = 1024; t = bid - 784; }
        else                { src = w2; dst = w2T; K = 1024; N = 256;  t = bid - 848; }
        int ntn = N >> 6;
        int k0 = (t / ntn) << 6, n0 = (t % ntn) << 6;
        int lane = tid & 63, wrow = tid >> 6;
        #pragma unroll
        for (int r = 0; r < 16; r++) {
            int k = wrow * 16 + r;
            tile[k][lane] = f2b(src[(size_t)(k0 + k) * N + n0 + lane]);
        }
        __syncthreads();
        #pragma unroll
        for (int r = 0; r < 16; r++) {
            int n = wrow * 16 + r;
            dst[(size_t)(n0 + n) * K + k0 + lane] = tile[lane][n];
        }
    } else {
        int row = (bid - 912) * 4 + (tid >> 6);
        int lane = tid & 63;
        float4 xv = *(const float4*)(x + (size_t)row * 256 + lane * 4);
        float v0 = xv.x, v1 = xv.y, v2 = xv.z, v3 = xv.w;
        float s = v0 + v1 + v2 + v3;
        #pragma unroll
        for (int m = 32; m; m >>= 1) s += __shfl_xor(s, m);
        float mu = s * 0.00390625f;
        float d0 = v0 - mu, d1 = v1 - mu, d2 = v2 - mu, d3 = v3 - mu;
        float ss = d0 * d0 + d1 * d1 + d2 * d2 + d3 * d3;
        #pragma unroll
        for (int m = 32; m; m >>= 1) ss += __shfl_xor(ss, m);
        float rs = rsqrtf(ss * 0.00390625f + 1e-5f);
        float4 g = *(const float4*)(g1 + lane * 4);
        float4 b = *(const float4*)(be1 + lane * 4);
        uint2 r;
        r.x = (u32)f2b(d0 * rs * g.x + b.x) | ((u32)f2b(d1 * rs * g.y + b.y) << 16);
        r.y = (u32)f2b(d2 * rs * g.z + b.z) | ((u32)f2b(d3 * rs * g.w + b.w) << 16);
        *(uint2*)(hout + (size_t)row * 256 + lane * 4) = r;
    }
}

// ---------------- 128x128 MFMA GEMM (qkv), async + LDS V-transpose ----------
template<bool HASBIAS, bool RELU, bool QKV>
__global__ __launch_bounds__(256) void gemm128(const u16* __restrict__ A,
                                               const u16* __restrict__ Bt,
                                               const float* __restrict__ bias,
                                               u16* __restrict__ out,
                                               u16* __restrict__ vout,
                                               int M, int N, int K) {
    __shared__ __align__(16) u16 SH[17408];      // As|Bs (32KB) / V-transpose (34KB)
    u16* As = SH;
    u16* Bs = SH + 128 * 64;
    const int tid = threadIdx.x, lane = tid & 63, w = tid >> 6;
    const int m0 = blockIdx.x * 128, n0 = blockIdx.y * 128;
    const int wm = (w & 1) * 64, wn = (w >> 1) * 64;
    const int fm = lane & 15, q = lane >> 4;

    float4v acc[4][4];
    #pragma unroll
    for (int i = 0; i < 4; i++)
        #pragma unroll
        for (int j = 0; j < 4; j++) acc[i][j] = (float4v){0.f, 0.f, 0.f, 0.f};

    const int kset = ((lane & 7) ^ (lane >> 3)) * 8;
    const u16* Ag = A  + (size_t)(m0 + w * 32 + (lane >> 3)) * K + kset;
    const u16* Bg = Bt + (size_t)(n0 + w * 32 + (lane >> 3)) * K + kset;
    u16* Asw = As + (w * 32) * 64;
    u16* Bsw = Bs + (w * 32) * 64;

    const int sw = fm & 7;
    for (int k0 = 0; k0 < K; k0 += 64) {
        __syncthreads();
        #pragma unroll
        for (int c = 0; c < 4; c++) {
            async_cp16(Ag + (size_t)c * 8 * K + k0, Asw + c * 8 * 64);
            async_cp16(Bg + (size_t)c * 8 * K + k0, Bsw + c * 8 * 64);
        }
        __syncthreads();
        #pragma unroll
        for (int kk = 0; kk < 64; kk += 32) {
            const int slot = (((kk >> 3) + q) ^ sw) * 8;
            short8v af[4], bf[4];
            #pragma unroll
            for (int mi = 0; mi < 4; mi++)
                af[mi] = *(const short8v*)&As[(wm + mi * 16 + fm) * 64 + slot];
            #pragma unroll
            for (int ni = 0; ni < 4; ni++)
                bf[ni] = *(const short8v*)&Bs[(wn + ni * 16 + fm) * 64 + slot];
            #pragma unroll
            for (int mi = 0; mi < 4; mi++)
                #pragma unroll
                for (int ni = 0; ni < 4; ni++)
                    acc[mi][ni] = __builtin_amdgcn_mfma_f32_16x16x32_bf16(
                        bf[ni], af[mi], acc[mi][ni], 0, 0, 0);
        }
    }

    if (QKV && n0 >= 512) {
        // V tile: transpose via LDS, then coalesced full-line stores.
        __syncthreads();
        #pragma unroll
        for (int mi = 0; mi < 4; mi++) {
            int ml = wm + mi * 16 + fm;
            #pragma unroll
            for (int ni = 0; ni < 4; ni++) {
                int nl = wn + ni * 16 + q * 4;
                #pragma unroll
                for (int r = 0; r < 4; r++)
                    SH[(nl + r) * 136 + ml] = f2b(acc[mi][ni][r]);
            }
        }
        __syncthreads();
        int r = tid & 127, c = (tid >> 7) << 6;
        int hd = (n0 - 512) + r;
        int b = m0 >> 10, t0 = m0 & 1023;
        u16* dst = vout + (size_t)(b * 256 + hd) * 1024 + t0 + c;
        const u16* srcT = SH + r * 136 + c;
        #pragma unroll
        for (int i = 0; i < 8; i++)
            *(uint4*)(dst + i * 8) = *(const uint4*)(srcT + i * 8);
        return;
    }

    #pragma unroll
    for (int mi = 0; mi < 4; mi++) {
        int row = m0 + wm + mi * 16 + fm;
        #pragma unroll
        for (int ni = 0; ni < 4; ni++) {
            int nb = n0 + wn + ni * 16 + q * 4;
            float v0 = acc[mi][ni][0], v1 = acc[mi][ni][1],
                  v2 = acc[mi][ni][2], v3 = acc[mi][ni][3];
            if (HASBIAS) {
                float4 bv = *(const float4*)&bias[nb];
                v0 += bv.x; v1 += bv.y; v2 += bv.z; v3 += bv.w;
            }
            if (RELU) {
                v0 = fmaxf(v0, 0.f); v1 = fmaxf(v1, 0.f);
                v2 = fmaxf(v2, 0.f); v3 = fmaxf(v3, 0.f);
            }
            size_t idx = (size_t)row * N + nb;
            uint2 ov;
            ov.x = (u32)f2b(v0) | ((u32)f2b(v1) << 16);
            ov.y = (u32)f2b(v2) | ((u32)f2b(v3) << 16);
            *(uint2*)&out[idx] = ov;
        }
    }
}

// ---------------- fused FFN: out = x2 + relu(h2@w1+b1)@w2 + b2 --------------
// 64-row blocks, 512 threads (8 waves = 2m x 4n), grid 256 = 1 block/CU.
// mid strip lives only in LDS. 32 B-tiles (4 nch x {gemm1 kc0-3, gemm2 kc0-3}),
// 2-deep prefetch with COUNTED vmcnt: raw s_barrier + s_waitcnt vmcnt(4);
// prefetched loads stay in flight across barriers (vmcnt(0) only at t=31).
// LDS 128KB: As 32K | Ms 32K | Bs 2x32K.
#define FFN_COMPUTE(ABASE, BBASE, ACC)                                            \
    _Pragma("unroll")                                                             \
    for (int kk = 0; kk < 64; kk += 32) {                                         \
        const int slot = (((kk >> 3) + q) ^ sw) * 8;                              \
        short8v af[2], bf[4];                                                     \
        _Pragma("unroll")                                                         \
        for (int mi = 0; mi < 2; mi++)                                            \
            af[mi] = *(const short8v*)&(ABASE)[(wm + mi * 16 + fm) * 64 + slot];  \
        _Pragma("unroll")                                                         \
        for (int ni = 0; ni < 4; ni++)                                            \
            bf[ni] = *(const short8v*)&(BBASE)[(wn + ni * 16 + fm) * 64 + slot];  \
        _Pragma("unroll")                                                         \
        for (int mi = 0; mi < 2; mi++)                                            \
            _Pragma("unroll")                                                     \
            for (int ni = 0; ni < 4; ni++)                                        \
                ACC[mi][ni] = __builtin_amdgcn_mfma_f32_16x16x32_bf16(            \
                    bf[ni], af[mi], ACC[mi][ni], 0, 0, 0);                        \
    }

__global__ __launch_bounds__(512, 2) void ffn_fused(const u16* __restrict__ h2,
                                                    const u16* __restrict__ w1T,
                                                    const float* __restrict__ b1,
                                                    const u16* __restrict__ w2T,
                                                    const float* __restrict__ b2,
                                                    const u16* __restrict__ x2b,
                                                    float* __restrict__ out) {
    __shared__ __align__(16) u16 SH[65536];   // 128KB
    u16* As = SH;             // [4 kc][64][64] h2 tile, kset-swizzled
    u16* Ms = SH + 16384;     // [4 kc][64][64] mid chunk, same swizzle
    u16* Bs = SH + 32768;     // 2 x [256][64] weight tile (double buffer)
    const int tid = threadIdx.x, lane = tid & 63, w = tid >> 6;
    const int m0 = blockIdx.x * 64;
    const int wm = (w & 1) * 32;              // m-half (32 rows)
    const int wn = (w >> 1) * 64;             // n-quarter (64 cols)
    const int fm = lane & 15, q = lane >> 4;
    const int sw = fm & 7;
    const int kset = ((lane & 7) ^ (lane >> 3)) * 8;
    const int rb = w * 8 + (lane >> 3);       // staging row 0..63

    // ---- B-tile issue helper (4 async_cp16 = 4 vmcnt ops per wave) ----
    auto issueB = [&](int t, u16* dst) {
        const int n2 = t >> 3, k2 = t & 3;
        if (((t >> 2) & 1) == 0) {
            const u16* src = w1T + (size_t)(n2 * 256 + rb) * 256 + k2 * 64 + kset;
            #pragma unroll
            for (int c = 0; c < 4; c++)
                async_cp16(src + (size_t)c * 64 * 256, dst + c * 4096);
        } else {
            const u16* src = w2T + (size_t)rb * 1024 + n2 * 256 + k2 * 64 + kset;
            #pragma unroll
            for (int c = 0; c < 4; c++)
                async_cp16(src + (size_t)c * 64 * 1024, dst + c * 4096);
        }
    };

    // ---- prologue: A tile (4 ops) + B tiles 0,1 (4 ops each) = 12 in flight
    const u16* Ag = h2 + (size_t)(m0 + rb) * 256 + kset;
    #pragma unroll
    for (int kc = 0; kc < 4; kc++)
        async_cp16(Ag + kc * 64, As + kc * 4096 + w * 512);
    issueB(0, Bs + w * 512);
    issueB(1, Bs + 16384 + w * 512);

    float4v acc1[2][4], acc2[2][4];
    #pragma unroll
    for (int i = 0; i < 2; i++)
        #pragma unroll
        for (int j = 0; j < 4; j++) acc2[i][j] = (float4v){0.f, 0.f, 0.f, 0.f};

    #pragma unroll 1
    for (int t = 0; t < 32; ++t) {
        const int nch = t >> 3, ph = (t >> 2) & 1, kc = t & 3;
        // wait: tile t's 4 loads landed (t+1's 4 stay in flight); A drained at t=0
        if (t == 31) asm volatile("s_waitcnt vmcnt(0)" ::: "memory");
        else         asm volatile("s_waitcnt vmcnt(4)" ::: "memory");
        __builtin_amdgcn_s_barrier();
        const u16* Bb = Bs + (t & 1) * 16384;
        // compute tile t
        if (ph == 0) {
            if (kc == 0) {
                #pragma unroll
                for (int i = 0; i < 2; i++)
                    #pragma unroll
                    for (int j = 0; j < 4; j++) acc1[i][j] = (float4v){0.f, 0.f, 0.f, 0.f};
            }
            const u16* Ab = As + kc * 4096;
            FFN_COMPUTE(Ab, Bb, acc1);
            if (kc == 3) {
                // bias + relu -> Ms (swizzled A layout for gemm2)
                #pragma unroll
                for (int ni = 0; ni < 4; ni++) {
                    const int c2 = wn + ni * 16 + q * 4;       // 0..255
                    const int kcM = c2 >> 6, cc = c2 & 63;
                    float4 bv = *(const float4*)&b1[nch * 256 + c2];
                    #pragma unroll
                    for (int mi = 0; mi < 2; mi++) {
                        const int row = wm + mi * 16 + fm;
                        float v0 = fmaxf(acc1[mi][ni][0] + bv.x, 0.f);
                        float v1 = fmaxf(acc1[mi][ni][1] + bv.y, 0.f);
                        float v2 = fmaxf(acc1[mi][ni][2] + bv.z, 0.f);
                        float v3 = fmaxf(acc1[mi][ni][3] + bv.w, 0.f);
                        uint2 pp;
                        pp.x = (u32)f2b(v0) | ((u32)f2b(v1) << 16);
                        pp.y = (u32)f2b(v2) | ((u32)f2b(v3) << 16);
                        *(uint2*)&Ms[kcM * 4096 + row * 64 +
                                     (((cc >> 3) ^ (row & 7)) * 8) + (cc & 7)] = pp;
                    }
                }
            }
        } else {
            const u16* Ab = Ms + kc * 4096;
            FFN_COMPUTE(Ab, Bb, acc2);
        }
        // cross-wave visibility of Ms ds_writes + own ds_reads retired,
        // then allow prefetch of t+2 to overwrite the buffer just computed.
        asm volatile("s_waitcnt lgkmcnt(0)" ::: "memory");
        __builtin_amdgcn_s_barrier();
        if (t + 2 < 32)
            issueB(t + 2, Bs + (t & 1) * 16384 + w * 512);
    }

    // ---- epilogue: out = acc2 + b2 + x2 (bf16 resid), fp32 stores ----
    #pragma unroll
    for (int mi = 0; mi < 2; mi++) {
        const int row = m0 + wm + mi * 16 + fm;
        #pragma unroll
        for (int ni = 0; ni < 4; ni++) {
            const int nb = wn + ni * 16 + q * 4;
            size_t idx = (size_t)row * 256 + nb;
            float4 bv = *(const float4*)&b2[nb];
            uint2 rv = *(const uint2*)&x2b[idx];
            float v0 = acc2[mi][ni][0] + bv.x + lo2f(rv.x);
            float v1 = acc2[mi][ni][1] + bv.y + hi2f(rv.x);
            float v2 = acc2[mi][ni][2] + bv.z + lo2f(rv.y);
            float v3 = acc2[mi][ni][3] + bv.w + hi2f(rv.y);
            *(float4*)&out[idx] = (float4){v0, v1, v2, v3};
        }
    }
}

// ---------------- proj GEMM + residual + LN2: 32-row blocks, 2/CU -----------
// x2 = att @ wpT^T + bp + x ; h2 = LN2(x2). grid 512. Waves: 2 x (16m x 128n),
// frags 1x8. Row stats: quad shuffles (own 128 ch) + LDS exchange with wave^2.
__global__ __launch_bounds__(256) void proj_ln2(const u16* __restrict__ att,
                                                const u16* __restrict__ wpT,
                                                const float* __restrict__ bp,
                                                const float* __restrict__ x,
                                                const float* __restrict__ g2,
                                                const float* __restrict__ be2,
                                                u16* __restrict__ x2b,
                                                u16* __restrict__ h2) {
    __shared__ __align__(16) u16 As[32 * 64];
    __shared__ __align__(16) u16 Bs[256 * 64];
    __shared__ float gs[256], bs[256], bps[256];
    __shared__ float ps[4][16], pq[4][16];
    const int tid = threadIdx.x, lane = tid & 63, w = tid >> 6;
    const int m0 = blockIdx.x * 32;
    const int wm = (w & 1) * 16, wn = (w >> 1) * 128;
    const int fm = lane & 15, q = lane >> 4;

    gs[tid] = g2[tid]; bs[tid] = be2[tid]; bps[tid] = bp[tid];

    float4v acc[8];
    #pragma unroll
    for (int i = 0; i < 8; i++) acc[i] = (float4v){0.f, 0.f, 0.f, 0.f};

    const int kset = ((lane & 7) ^ (lane >> 3)) * 8;
    const u16* Ag = att + (size_t)(m0 + w * 8 + (lane >> 3)) * 256 + kset;
    const u16* Bg = wpT + (size_t)(w * 64 + (lane >> 3)) * 256 + kset;
    u16* Asw = As + (w * 8) * 64;
    u16* Bsw = Bs + (w * 64) * 64;

    const int sw = fm & 7;
    for (int k0 = 0; k0 < 256; k0 += 64) {
        __syncthreads();
        async_cp16(Ag + k0, Asw);
        #pragma unroll
        for (int c = 0; c < 8; c++)
            async_cp16(Bg + (size_t)c * 8 * 256 + k0, Bsw + c * 8 * 64);
        __syncthreads();
        #pragma unroll
        for (int kk = 0; kk < 64; kk += 32) {
            const int slot = (((kk >> 3) + q) ^ sw) * 8;
            short8v af = *(const short8v*)&As[(wm + fm) * 64 + slot];
            #pragma unroll
            for (int ni = 0; ni < 8; ni++) {
                short8v bf = *(const short8v*)&Bs[(wn + ni * 16 + fm) * 64 + slot];
                acc[ni] = __builtin_amdgcn_mfma_f32_16x16x32_bf16(bf, af, acc[ni], 0, 0, 0);
            }
        }
    }

    // epilogue: row m = m0+wm+fm; thread covers 32 of its 256 channels
    int m = m0 + wm + fm;
    float v[8][4];
    float s = 0.f, sq = 0.f;
    #pragma unroll
    for (int ni = 0; ni < 8; ni++) {
        int nb = wn + ni * 16 + q * 4;
        float4 xv = *(const float4*)(x + (size_t)m * 256 + nb);
        float4 bv = *(const float4*)&bps[nb];
        #pragma unroll
        for (int r = 0; r < 4; r++) {
            float t = acc[ni][r] + (&bv.x)[r] + (&xv.x)[r];
            v[ni][r] = t;
            s += t; sq += t * t;
        }
    }
    s += __shfl_xor(s, 16);  s += __shfl_xor(s, 32);   // sum over q -> 128 ch
    sq += __shfl_xor(sq, 16); sq += __shfl_xor(sq, 32);
    if (q == 0) { ps[w][fm] = s; pq[w][fm] = sq; }
    __syncthreads();
    s = ps[w][fm] + ps[w ^ 2][fm];                      // + partner wave's 128 ch
    sq = pq[w][fm] + pq[w ^ 2][fm];
    float mu = s * 0.00390625f;
    float rs = rsqrtf(sq * 0.00390625f - mu * mu + 1e-5f);
    #pragma unroll
    for (int ni = 0; ni < 8; ni++) {
        int nb = wn + ni * 16 + q * 4;
        size_t idx = (size_t)m * 256 + nb;
        float4 gv = *(const float4*)&gs[nb];
        float4 bv = *(const float4*)&bs[nb];
        uint2 xo, ho;
        xo.x = (u32)f2b(v[ni][0]) | ((u32)f2b(v[ni][1]) << 16);
        xo.y = (u32)f2b(v[ni][2]) | ((u32)f2b(v[ni][3]) << 16);
        float h0 = (v[ni][0] - mu) * rs * gv.x + bv.x;
        float h1 = (v[ni][1] - mu) * rs * gv.y + bv.y;
        float h2v = (v[ni][2] - mu) * rs * gv.z + bv.z;
        float h3 = (v[ni][3] - mu) * rs * gv.w + bv.w;
        ho.x = (u32)f2b(h0) | ((u32)f2b(h1) << 16);
        ho.y = (u32)f2b(h2v) | ((u32)f2b(h3) << 16);
        *(uint2*)&x2b[idx] = xo;
        *(uint2*)&h2[idx] = ho;    // in-place over att: own rows, post-k-loop
    }
}

// ---------------- MFMA flash attention: single sweep, dual q-tile -----------
__global__ __launch_bounds__(256) void attn_mfma(const u16* __restrict__ qk,
                                                 const u16* __restrict__ vtg,
                                                 u16* __restrict__ att) {
    const int T = 1024;
    int jj = (blockIdx.x + (blockIdx.y >> 3)) & 7;
    int b = blockIdx.y >> 3, hh = blockIdx.y & 7;
    int tid = threadIdx.x;
    int lane = tid & 63, w = tid >> 6;
    int fm = lane & 15, q = lane >> 4;

    __shared__ __align__(16) u16 Ks[64][72];
    __shared__ __align__(16) u16 Vt[32][72];
    __shared__ __align__(16) u16 Pl[4][16][72];

    size_t base = (size_t)b * T * 512;
    const u16* kb = qk + base + 256 + hh * 32;
    const u16* vt = vtg + (size_t)((b * 8 + hh) * 32) * 1024;
    const int krow = tid >> 2, kcol = (tid & 3) * 8;
    const int vd = tid >> 3, vs = (tid & 7) * 8;

    int qa0 = jj * 64, qb0 = (15 - jj) * 64;
    int tqa = qa0 + w * 16 + fm, tqb = qb0 + w * 16 + fm;
    short8v qfa = *(const short8v*)(qk + base + (size_t)tqa * 512 + hh * 32 + q * 8);
    short8v qfb = *(const short8v*)(qk + base + (size_t)tqb * 512 + hh * 32 + q * 8);
    float4v oa0 = {0.f, 0.f, 0.f, 0.f}, oa1 = {0.f, 0.f, 0.f, 0.f};
    float4v ob0 = {0.f, 0.f, 0.f, 0.f}, ob1 = {0.f, 0.f, 0.f, 0.f};
    float la = 0.f, lb = 0.f;
    int wqa = qa0 + w * 16, wqb = qb0 + w * 16;
    int nIter = 16 - jj;

    uint4 kreg = *(const uint4*)(kb + (size_t)krow * 512 + kcol);
    uint4 vreg = *(const uint4*)(vt + (size_t)vd * 1024 + vs);

    for (int it = 0; it < nIter; ++it) {
        int s0 = it << 6;
        __syncthreads();
        *(uint4*)&Ks[krow][kcol] = kreg;
        *(uint4*)&Vt[vd][vs] = vreg;
        __syncthreads();
        if (it + 1 < nIter) {
            int ns0 = s0 + 64;
            kreg = *(const uint4*)(kb + (size_t)(ns0 + krow) * 512 + kcol);
            vreg = *(const uint4*)(vt + (size_t)vd * 1024 + ns0 + vs);
        }
        short8v kf0 = *(const short8v*)&Ks[fm][q * 8];
        short8v kf1 = *(const short8v*)&Ks[16 + fm][q * 8];
        short8v kf2 = *(const short8v*)&Ks[32 + fm][q * 8];
        short8v kf3 = *(const short8v*)&Ks[48 + fm][q * 8];
        short8v vf00 = *(const short8v*)&Vt[fm][q * 8];
        short8v vf01 = *(const short8v*)&Vt[fm][32 + q * 8];
        short8v vf10 = *(const short8v*)&Vt[16 + fm][q * 8];
        short8v vf11 = *(const short8v*)&Vt[16 + fm][32 + q * 8];
        float4v z = {0.f, 0.f, 0.f, 0.f};

        #pragma unroll
        for (int t2 = 0; t2 < 2; t2++) {       // t2=0: tile b (large), 1: tile a
            int wq0 = t2 ? wqa : wqb;
            if (s0 >= wq0 + 16) continue;      // wave-uniform causal skip
            int tq = t2 ? tqa : tqb;
            short8v qf = t2 ? qfa : qfb;
            float4v s_0 = __builtin_amdgcn_mfma_f32_16x16x32_bf16(kf0, qf, z, 0, 0, 0);
            float4v s_1 = __builtin_amdgcn_mfma_f32_16x16x32_bf16(kf1, qf, z, 0, 0, 0);
            float4v s_2 = __builtin_amdgcn_mfma_f32_16x16x32_bf16(kf2, qf, z, 0, 0, 0);
            float4v s_3 = __builtin_amdgcn_mfma_f32_16x16x32_bf16(kf3, qf, z, 0, 0, 0);
            float p[16];
            #pragma unroll
            for (int r = 0; r < 4; r++) {
                p[r] = exp2f(s_0[r]); p[4 + r] = exp2f(s_1[r]);
                p[8 + r] = exp2f(s_2[r]); p[12 + r] = exp2f(s_3[r]);
            }
            if (s0 + 63 > wq0) {               // diagonal region: causal mask
                int sb = s0 + q * 4;
                #pragma unroll
                for (int c = 0; c < 4; c++)
                    #pragma unroll
                    for (int r = 0; r < 4; r++)
                        if (sb + c * 16 + r > tq) p[c * 4 + r] = 0.f;
            }
            float rsum = 0.f;
            #pragma unroll
            for (int i = 0; i < 16; i++) rsum += p[i];
            rsum += __shfl_xor(rsum, 16);
            rsum += __shfl_xor(rsum, 32);
            if (t2) la += rsum; else lb += rsum;

            #pragma unroll
            for (int c = 0; c < 4; c++) {
                uint2 pp;
                pp.x = pk2_rtz(p[c * 4 + 0], p[c * 4 + 1]);
                pp.y = pk2_rtz(p[c * 4 + 2], p[c * 4 + 3]);
                *(uint2*)&Pl[w][fm][c * 16 + q * 4] = pp;   // wave-internal
            }
            short8v pf0 = *(const short8v*)&Pl[w][fm][q * 8];
            short8v pf1 = *(const short8v*)&Pl[w][fm][32 + q * 8];
            if (t2) {
                oa0 = __builtin_amdgcn_mfma_f32_16x16x32_bf16(vf00, pf0, oa0, 0, 0, 0);
                oa0 = __builtin_amdgcn_mfma_f32_16x16x32_bf16(vf01, pf1, oa0, 0, 0, 0);
                oa1 = __builtin_amdgcn_mfma_f32_16x16x32_bf16(vf10, pf0, oa1, 0, 0, 0);
                oa1 = __builtin_amdgcn_mfma_f32_16x16x32_bf16(vf11, pf1, oa1, 0, 0, 0);
            } else {
                ob0 = __builtin_amdgcn_mfma_f32_16x16x32_bf16(vf00, pf0, ob0, 0, 0, 0);
                ob0 = __builtin_amdgcn_mfma_f32_16x16x32_bf16(vf01, pf1, ob0, 0, 0, 0);
                ob1 = __builtin_amdgcn_mfma_f32_16x16x32_bf16(vf10, pf0, ob1, 0, 0, 0);
                ob1 = __builtin_amdgcn_mfma_f32_16x16x32_bf16(vf11, pf1, ob1, 0, 0, 0);
            }
        }
    }

    #pragma unroll
    for (int t2 = 0; t2 < 2; t2++) {
        float inv = 1.f / (t2 ? la : lb);
        float4v o0 = t2 ? oa0 : ob0, o1 = t2 ? oa1 : ob1;
        int tq = t2 ? tqa : tqb;
        uint2 r0, r1;
        r0.x = (u32)f2b(o0[0] * inv) | ((u32)f2b(o0[1] * inv) << 16);
        r0.y = (u32)f2b(o0[2] * inv) | ((u32)f2b(o0[3] * inv) << 16);
        r1.x = (u32)f2b(o1[0] * inv) | ((u32)f2b(o1[1] * inv) << 16);
        r1.y = (u32)f2b(o1[2] * inv) | ((u32)f2b(o1[3] * inv) << 16);
        size_t o = (size_t)(b * T + tq) * 256 + hh * 32;
        *(uint2*)(att + o + q * 4) = r0;
        *(uint2*)(att + o + 16 + q * 4) = r1;
    }
}

// ---------------- launch ----------------
extern "C" void kernel_launch(void* const* d_in, const int* in_sizes, int n_in,
                              void* d_out, int out_size, void* d_ws, size_t ws_size,
                              hipStream_t stream) {
    const int BT = 16 * 1024;
    const float* x      = (const float*)d_in[0];
    const float* wq     = (const float*)d_in[1];
    const float* wk     = (const float*)d_in[2];
    const float* wv     = (const float*)d_in[3];
    const float* w_proj = (const float*)d_in[4];
    const float* b_proj = (const float*)d_in[5];
    const float* w1     = (const float*)d_in[6];
    const float* b1     = (const float*)d_in[7];
    const float* w2     = (const float*)d_in[8];
    const float* b2     = (const float*)d_in[9];
    const float* ln1_g  = (const float*)d_in[10];
    const float* ln1_b  = (const float*)d_in[11];
    const float* ln2_g  = (const float*)d_in[12];
    const float* ln2_b  = (const float*)d_in[13];

    // Workspace (~49.5 MiB):
    //   [0, 8M)   x2b (bf16 x2)
    //   [8M,16M)  hbuf: h -> att -> h2  [serial, proj_ln2 in-place]
    //   [16M,32M) qk [BT,512] | [32M,48M) vtg  -> dead after attn
    //   [48M...)  packed weights (1.5M)
    char* ws = (char*)d_ws;
    const size_t MB = 1024 * 1024;
    u16*  x2b   = (u16*)(ws + 0);
    u16*  hbuf  = (u16*)(ws + 8 * MB);
    u16*  qk    = (u16*)(ws + 16 * MB);
    u16*  vtg   = (u16*)(ws + 32 * MB);
    u16*  wqkvT = (u16*)(ws + 48 * MB);
    u16*  wpT   = (u16*)(ws + 48 * MB + 0x60000);
    u16*  w1T   = (u16*)(ws + 48 * MB + 0x80000);
    u16*  w2T   = (u16*)(ws + 48 * MB + 0x100000);

    prep_ln1<<<5008, 256, 0, stream>>>(wq, wk, wv, w_proj, w1, w2, x, ln1_g, ln1_b,
                                       wqkvT, wpT, w1T, w2T, hbuf);
    // qk | vtg = h @ [Wq'|Wk|Wv]
    gemm128<false, false, true><<<dim3(128, 6), 256, 0, stream>>>(
        hbuf, wqkvT, nullptr, qk, vtg, BT, 512, 256);
    // att = flash attention (writes over h)
    attn_mfma<<<dim3(8, 128), 256, 0, stream>>>(qk, vtg, hbuf);
    // x2 = x + att @ w_proj + b_proj ; h2 = LN2(x2)  [32-row blocks, 2/CU]
    proj_ln2<<<512, 256, 0, stream>>>(hbuf, wpT, b_proj, x, ln2_g, ln2_b, x2b, hbuf);
    // out = x2 + relu(h2 @ w1 + b1) @ w2 + b2  [64-row blocks, counted-vmcnt dbuf]
    ffn_fused<<<256, 512, 0, stream>>>(hbuf, w1T, b1, w2T, b2, x2b, (float*)d_out);
}

// Round 4
// 178.721 us; speedup vs baseline: 1.0556x; 1.0556x over previous
//
#include <hip/hip_runtime.h>

// EncoderBlock on MI355X. Round 18: ffn_fused v3 — A-tile in registers
// (64 VGPR), triple-buffered B in LDS (3x32K) + Ms (32K) = 128KB, ONE raw
// s_barrier + ONE counted "s_waitcnt vmcnt(4)" per tile, fully unrolled so
// all 32 tiles' addresses constant-fold. lgkmcnt(0) only after Ms writes.
// Everything else identical to r16 (183.6 µs). B=16 T=1024 C=256 H=8 D=32.

typedef unsigned short u16;
typedef unsigned int u32;
typedef __attribute__((ext_vector_type(8))) short short8v;  // 8 bf16 MFMA A/B frag
typedef __attribute__((ext_vector_type(4))) float float4v;  // MFMA C/D frag

__device__ __forceinline__ float b2f(u16 u) { union { u32 i; float f; } v; v.i = (u32)u << 16; return v.f; }
__device__ __forceinline__ float lo2f(u32 u) { union { u32 i; float f; } v; v.i = u << 16; return v.f; }
__device__ __forceinline__ float hi2f(u32 u) { union { u32 i; float f; } v; v.i = u & 0xffff0000u; return v.f; }
__device__ __forceinline__ u16 f2b(float f) {
    union { float f; u32 i; } v; v.f = f;
    u32 r = v.i + 0x7fffu + ((v.i >> 16) & 1u);  // RTNE
    return (u16)(r >> 16);
}
__device__ __forceinline__ u32 pk2_rtz(float a, float b) {
    return (__float_as_uint(a) >> 16) | (__float_as_uint(b) & 0xffff0000u);
}
__device__ __forceinline__ void async_cp16(const u16* g, u16* l) {
    __builtin_amdgcn_global_load_lds((const __attribute__((address_space(1))) void*)g,
                                     (__attribute__((address_space(3))) void*)l, 16, 0, 0);
}

// ---------------- fused prep (wqkv pack + 3 transposes) + LN1 ---------------
__global__ __launch_bounds__(256) void prep_ln1(const float* __restrict__ wq,
                                                const float* __restrict__ wk,
                                                const float* __restrict__ wv,
                                                const float* __restrict__ wp,
                                                const float* __restrict__ w1,
                                                const float* __restrict__ w2,
                                                const float* __restrict__ x,
                                                const float* __restrict__ g1,
                                                const float* __restrict__ be1,
                                                u16* __restrict__ wqkvT,
                                                u16* __restrict__ wpT,
                                                u16* __restrict__ w1T,
                                                u16* __restrict__ w2T,
                                                u16* __restrict__ hout) {
    __shared__ u16 tile[64][65];
    int bid = blockIdx.x, tid = threadIdx.x;
    if (bid < 768) {
        int i = bid * 256 + tid;
        int n = i >> 8, k = i & 255;
        int which = n >> 8, nn = n & 255;
        const float* w = which == 0 ? wq : (which == 1 ? wk : wv);
        float v = w[((nn >> 5) * 256 + k) * 32 + (nn & 31)];   // w[h][k][d]
        if (which == 0) v *= 0.09016844f;                      // (1/16)*log2(e)
        wqkvT[i] = f2b(v);
    } else if (bid < 912) {
        const float* src; u16* dst; int K, N, t;
        if (bid < 784)      { src = wp; dst = wpT; K = 256;  N = 256;  t = bid - 768; }
        else if (bid < 848) { src = w1; dst = w1T; K = 256;  N = 1024; t = bid - 784; }
        else                { src = w2; dst = w2T; K = 1024; N = 256;  t = bid - 848; }
        int ntn = N >> 6;
        int k0 = (t / ntn) << 6, n0 = (t % ntn) << 6;
        int lane = tid & 63, wrow = tid >> 6;
        #pragma unroll
        for (int r = 0; r < 16; r++) {
            int k = wrow * 16 + r;
            tile[k][lane] = f2b(src[(size_t)(k0 + k) * N + n0 + lane]);
        }
        __syncthreads();
        #pragma unroll
        for (int r = 0; r < 16; r++) {
            int n = wrow * 16 + r;
            dst[(size_t)(n0 + n) * K + k0 + lane] = tile[lane][n];
        }
    } else {
        int row = (bid - 912) * 4 + (tid >> 6);
        int lane = tid & 63;
        float4 xv = *(const float4*)(x + (size_t)row * 256 + lane * 4);
        float v0 = xv.x, v1 = xv.y, v2 = xv.z, v3 = xv.w;
        float s = v0 + v1 + v2 + v3;
        #pragma unroll
        for (int m = 32; m; m >>= 1) s += __shfl_xor(s, m);
        float mu = s * 0.00390625f;
        float d0 = v0 - mu, d1 = v1 - mu, d2 = v2 - mu, d3 = v3 - mu;
        float ss = d0 * d0 + d1 * d1 + d2 * d2 + d3 * d3;
        #pragma unroll
        for (int m = 32; m; m >>= 1) ss += __shfl_xor(ss, m);
        float rs = rsqrtf(ss * 0.00390625f + 1e-5f);
        float4 g = *(const float4*)(g1 + lane * 4);
        float4 b = *(const float4*)(be1 + lane * 4);
        uint2 r;
        r.x = (u32)f2b(d0 * rs * g.x + b.x) | ((u32)f2b(d1 * rs * g.y + b.y) << 16);
        r.y = (u32)f2b(d2 * rs * g.z + b.z) | ((u32)f2b(d3 * rs * g.w + b.w) << 16);
        *(uint2*)(hout + (size_t)row * 256 + lane * 4) = r;
    }
}

// ---------------- 128x128 MFMA GEMM (qkv), async + LDS V-transpose ----------
template<bool HASBIAS, bool RELU, bool QKV>
__global__ __launch_bounds__(256) void gemm128(const u16* __restrict__ A,
                                               const u16* __restrict__ Bt,
                                               const float* __restrict__ bias,
                                               u16* __restrict__ out,
                                               u16* __restrict__ vout,
                                               int M, int N, int K) {
    __shared__ __align__(16) u16 SH[17408];      // As|Bs (32KB) / V-transpose (34KB)
    u16* As = SH;
    u16* Bs = SH + 128 * 64;
    const int tid = threadIdx.x, lane = tid & 63, w = tid >> 6;
    const int m0 = blockIdx.x * 128, n0 = blockIdx.y * 128;
    const int wm = (w & 1) * 64, wn = (w >> 1) * 64;
    const int fm = lane & 15, q = lane >> 4;

    float4v acc[4][4];
    #pragma unroll
    for (int i = 0; i < 4; i++)
        #pragma unroll
        for (int j = 0; j < 4; j++) acc[i][j] = (float4v){0.f, 0.f, 0.f, 0.f};

    const int kset = ((lane & 7) ^ (lane >> 3)) * 8;
    const u16* Ag = A  + (size_t)(m0 + w * 32 + (lane >> 3)) * K + kset;
    const u16* Bg = Bt + (size_t)(n0 + w * 32 + (lane >> 3)) * K + kset;
    u16* Asw = As + (w * 32) * 64;
    u16* Bsw = Bs + (w * 32) * 64;

    const int sw = fm & 7;
    for (int k0 = 0; k0 < K; k0 += 64) {
        __syncthreads();
        #pragma unroll
        for (int c = 0; c < 4; c++) {
            async_cp16(Ag + (size_t)c * 8 * K + k0, Asw + c * 8 * 64);
            async_cp16(Bg + (size_t)c * 8 * K + k0, Bsw + c * 8 * 64);
        }
        __syncthreads();
        #pragma unroll
        for (int kk = 0; kk < 64; kk += 32) {
            const int slot = (((kk >> 3) + q) ^ sw) * 8;
            short8v af[4], bf[4];
            #pragma unroll
            for (int mi = 0; mi < 4; mi++)
                af[mi] = *(const short8v*)&As[(wm + mi * 16 + fm) * 64 + slot];
            #pragma unroll
            for (int ni = 0; ni < 4; ni++)
                bf[ni] = *(const short8v*)&Bs[(wn + ni * 16 + fm) * 64 + slot];
            #pragma unroll
            for (int mi = 0; mi < 4; mi++)
                #pragma unroll
                for (int ni = 0; ni < 4; ni++)
                    acc[mi][ni] = __builtin_amdgcn_mfma_f32_16x16x32_bf16(
                        bf[ni], af[mi], acc[mi][ni], 0, 0, 0);
        }
    }

    if (QKV && n0 >= 512) {
        // V tile: transpose via LDS, then coalesced full-line stores.
        __syncthreads();
        #pragma unroll
        for (int mi = 0; mi < 4; mi++) {
            int ml = wm + mi * 16 + fm;
            #pragma unroll
            for (int ni = 0; ni < 4; ni++) {
                int nl = wn + ni * 16 + q * 4;
                #pragma unroll
                for (int r = 0; r < 4; r++)
                    SH[(nl + r) * 136 + ml] = f2b(acc[mi][ni][r]);
            }
        }
        __syncthreads();
        int r = tid & 127, c = (tid >> 7) << 6;
        int hd = (n0 - 512) + r;
        int b = m0 >> 10, t0 = m0 & 1023;
        u16* dst = vout + (size_t)(b * 256 + hd) * 1024 + t0 + c;
        const u16* srcT = SH + r * 136 + c;
        #pragma unroll
        for (int i = 0; i < 8; i++)
            *(uint4*)(dst + i * 8) = *(const uint4*)(srcT + i * 8);
        return;
    }

    #pragma unroll
    for (int mi = 0; mi < 4; mi++) {
        int row = m0 + wm + mi * 16 + fm;
        #pragma unroll
        for (int ni = 0; ni < 4; ni++) {
            int nb = n0 + wn + ni * 16 + q * 4;
            float v0 = acc[mi][ni][0], v1 = acc[mi][ni][1],
                  v2 = acc[mi][ni][2], v3 = acc[mi][ni][3];
            if (HASBIAS) {
                float4 bv = *(const float4*)&bias[nb];
                v0 += bv.x; v1 += bv.y; v2 += bv.z; v3 += bv.w;
            }
            if (RELU) {
                v0 = fmaxf(v0, 0.f); v1 = fmaxf(v1, 0.f);
                v2 = fmaxf(v2, 0.f); v3 = fmaxf(v3, 0.f);
            }
            size_t idx = (size_t)row * N + nb;
            uint2 ov;
            ov.x = (u32)f2b(v0) | ((u32)f2b(v1) << 16);
            ov.y = (u32)f2b(v2) | ((u32)f2b(v3) << 16);
            *(uint2*)&out[idx] = ov;
        }
    }
}

// ---------------- fused FFN: out = x2 + relu(h2@w1+b1)@w2 + b2 --------------
// 64-row blocks, 512 threads (8 waves = 2m x 4n), grid 256 = 1 block/CU.
// A-tile in registers (16 short8v/thread). mid strip in LDS (Ms). B-tiles
// triple-buffered; per tile: s_waitcnt vmcnt(4) -> s_barrier -> issue B(t+2)
// into buf (t+2)%3 (= buf read at t-1, safe) -> compute. Fully unrolled.
// lgkmcnt(0) only after the 4 Ms-write tiles. LDS 128KB: Ms 32K | Bs 3x32K.
__global__ __launch_bounds__(512, 2) void ffn_fused(const u16* __restrict__ h2,
                                                    const u16* __restrict__ w1T,
                                                    const float* __restrict__ b1,
                                                    const u16* __restrict__ w2T,
                                                    const float* __restrict__ b2,
                                                    const u16* __restrict__ x2b,
                                                    float* __restrict__ out) {
    __shared__ __align__(16) u16 SH[65536];   // 128KB
    u16* Ms = SH;             // [4 kc][64][64] mid chunk, kset-swizzled
    u16* Bs = SH + 16384;     // 3 x [256][64] weight tile (triple buffer)
    const int tid = threadIdx.x, lane = tid & 63, w = tid >> 6;
    const int m0 = blockIdx.x * 64;
    const int wm = (w & 1) * 32;              // m-half (32 rows)
    const int wn = (w >> 1) * 64;             // n-quarter (64 cols)
    const int fm = lane & 15, q = lane >> 4;
    const int sw = fm & 7;
    const int kset = ((lane & 7) ^ (lane >> 3)) * 8;
    const int rb = w * 8 + (lane >> 3);       // staging row 0..63

    // ---- A-tile into registers: ar[kcn][mi] = h2[row(mi)][kcn*32 + q*8] ----
    short8v ar[8][2];
    {
        const u16* Abase = h2 + (size_t)(m0 + wm + fm) * 256 + q * 8;
        #pragma unroll
        for (int kcn = 0; kcn < 8; kcn++)
            #pragma unroll
            for (int mi = 0; mi < 2; mi++)
                ar[kcn][mi] = *(const short8v*)(Abase + (size_t)mi * 16 * 256 + kcn * 32);
    }

    // ---- B-tile issue helper (4 async_cp16 = 4 vmcnt ops per wave) ----
    auto issueB = [&](int t, u16* dst) {
        const int n2 = t >> 3, k2 = t & 3;
        if (((t >> 2) & 1) == 0) {
            const u16* src = w1T + (size_t)(n2 * 256 + rb) * 256 + k2 * 64 + kset;
            #pragma unroll
            for (int c = 0; c < 4; c++)
                async_cp16(src + (size_t)c * 64 * 256, dst + c * 4096);
        } else {
            const u16* src = w2T + (size_t)rb * 1024 + n2 * 256 + k2 * 64 + kset;
            #pragma unroll
            for (int c = 0; c < 4; c++)
                async_cp16(src + (size_t)c * 64 * 1024, dst + c * 4096);
        }
    };

    // ---- prologue: B tiles 0,1 (8 vm ops after the 16 A-loads) ----
    issueB(0, Bs + w * 512);
    issueB(1, Bs + 16384 + w * 512);

    float4v acc1[2][4], acc2[2][4];
    #pragma unroll
    for (int i = 0; i < 2; i++)
        #pragma unroll
        for (int j = 0; j < 4; j++) acc2[i][j] = (float4v){0.f, 0.f, 0.f, 0.f};

    #pragma unroll
    for (int t = 0; t < 32; ++t) {
        const int nch = t >> 3, ph = (t >> 2) & 1, kc = t & 3;
        // B(t) landed; B(t+1) stays in flight (4 ops). Also drains A at t=0.
        if (t == 31) asm volatile("s_waitcnt vmcnt(0)" ::: "memory");
        else         asm volatile("s_waitcnt vmcnt(4)" ::: "memory");
        __builtin_amdgcn_s_barrier();
        // issue B(t+2) into buf (t+2)%3 == buf read at t-1 (all done by barrier)
        if (t + 2 < 32)
            issueB(t + 2, Bs + ((t + 2) % 3) * 16384 + w * 512);
        const u16* Bb = Bs + (t % 3) * 16384;
        if (ph == 0) {
            if (kc == 0) {
                #pragma unroll
                for (int i = 0; i < 2; i++)
                    #pragma unroll
                    for (int j = 0; j < 4; j++) acc1[i][j] = (float4v){0.f, 0.f, 0.f, 0.f};
            }
            #pragma unroll
            for (int kk = 0; kk < 64; kk += 32) {
                const int slot = (((kk >> 3) + q) ^ sw) * 8;
                short8v bf[4];
                #pragma unroll
                for (int ni = 0; ni < 4; ni++)
                    bf[ni] = *(const short8v*)&Bb[(wn + ni * 16 + fm) * 64 + slot];
                #pragma unroll
                for (int mi = 0; mi < 2; mi++)
                    #pragma unroll
                    for (int ni = 0; ni < 4; ni++)
                        acc1[mi][ni] = __builtin_amdgcn_mfma_f32_16x16x32_bf16(
                            bf[ni], ar[kc * 2 + (kk >> 5)][mi], acc1[mi][ni], 0, 0, 0);
            }
            if (kc == 3) {
                // bias + relu -> Ms (swizzled A layout for gemm2)
                #pragma unroll
                for (int ni = 0; ni < 4; ni++) {
                    const int c2 = wn + ni * 16 + q * 4;       // 0..255
                    const int kcM = c2 >> 6, cc = c2 & 63;
                    float4 bv = *(const float4*)&b1[nch * 256 + c2];
                    #pragma unroll
                    for (int mi = 0; mi < 2; mi++) {
                        const int row = wm + mi * 16 + fm;
                        float v0 = fmaxf(acc1[mi][ni][0] + bv.x, 0.f);
                        float v1 = fmaxf(acc1[mi][ni][1] + bv.y, 0.f);
                        float v2 = fmaxf(acc1[mi][ni][2] + bv.z, 0.f);
                        float v3 = fmaxf(acc1[mi][ni][3] + bv.w, 0.f);
                        uint2 pp;
                        pp.x = (u32)f2b(v0) | ((u32)f2b(v1) << 16);
                        pp.y = (u32)f2b(v2) | ((u32)f2b(v3) << 16);
                        *(uint2*)&Ms[kcM * 4096 + row * 64 +
                                     (((cc >> 3) ^ (row & 7)) * 8) + (cc & 7)] = pp;
                    }
                }
                // publish Ms before next barrier (cross-wave read at t+1)
                asm volatile("s_waitcnt lgkmcnt(0)" ::: "memory");
            }
        } else {
            const u16* Ab = Ms + kc * 4096;
            #pragma unroll
            for (int kk = 0; kk < 64; kk += 32) {
                const int slot = (((kk >> 3) + q) ^ sw) * 8;
                short8v af[2], bf[4];
                #pragma unroll
                for (int mi = 0; mi < 2; mi++)
                    af[mi] = *(const short8v*)&Ab[(wm + mi * 16 + fm) * 64 + slot];
                #pragma unroll
                for (int ni = 0; ni < 4; ni++)
                    bf[ni] = *(const short8v*)&Bb[(wn + ni * 16 + fm) * 64 + slot];
                #pragma unroll
                for (int mi = 0; mi < 2; mi++)
                    #pragma unroll
                    for (int ni = 0; ni < 4; ni++)
                        acc2[mi][ni] = __builtin_amdgcn_mfma_f32_16x16x32_bf16(
                            bf[ni], af[mi], acc2[mi][ni], 0, 0, 0);
            }
        }
    }

    // ---- epilogue: out = acc2 + b2 + x2 (bf16 resid), fp32 stores ----
    #pragma unroll
    for (int mi = 0; mi < 2; mi++) {
        const int row = m0 + wm + mi * 16 + fm;
        #pragma unroll
        for (int ni = 0; ni < 4; ni++) {
            const int nb = wn + ni * 16 + q * 4;
            size_t idx = (size_t)row * 256 + nb;
            float4 bv = *(const float4*)&b2[nb];
            uint2 rv = *(const uint2*)&x2b[idx];
            float v0 = acc2[mi][ni][0] + bv.x + lo2f(rv.x);
            float v1 = acc2[mi][ni][1] + bv.y + hi2f(rv.x);
            float v2 = acc2[mi][ni][2] + bv.z + lo2f(rv.y);
            float v3 = acc2[mi][ni][3] + bv.w + hi2f(rv.y);
            *(float4*)&out[idx] = (float4){v0, v1, v2, v3};
        }
    }
}

// ---------------- proj GEMM + residual + LN2: 32-row blocks, 2/CU -----------
// x2 = att @ wpT^T + bp + x ; h2 = LN2(x2). grid 512. Waves: 2 x (16m x 128n),
// frags 1x8. Row stats: quad shuffles (own 128 ch) + LDS exchange with wave^2.
__global__ __launch_bounds__(256) void proj_ln2(const u16* __restrict__ att,
                                                const u16* __restrict__ wpT,
                                                const float* __restrict__ bp,
                                                const float* __restrict__ x,
                                                const float* __restrict__ g2,
                                                const float* __restrict__ be2,
                                                u16* __restrict__ x2b,
                                                u16* __restrict__ h2) {
    __shared__ __align__(16) u16 As[32 * 64];
    __shared__ __align__(16) u16 Bs[256 * 64];
    __shared__ float gs[256], bs[256], bps[256];
    __shared__ float ps[4][16], pq[4][16];
    const int tid = threadIdx.x, lane = tid & 63, w = tid >> 6;
    const int m0 = blockIdx.x * 32;
    const int wm = (w & 1) * 16, wn = (w >> 1) * 128;
    const int fm = lane & 15, q = lane >> 4;

    gs[tid] = g2[tid]; bs[tid] = be2[tid]; bps[tid] = bp[tid];

    float4v acc[8];
    #pragma unroll
    for (int i = 0; i < 8; i++) acc[i] = (float4v){0.f, 0.f, 0.f, 0.f};

    const int kset = ((lane & 7) ^ (lane >> 3)) * 8;
    const u16* Ag = att + (size_t)(m0 + w * 8 + (lane >> 3)) * 256 + kset;
    const u16* Bg = wpT + (size_t)(w * 64 + (lane >> 3)) * 256 + kset;
    u16* Asw = As + (w * 8) * 64;
    u16* Bsw = Bs + (w * 64) * 64;

    const int sw = fm & 7;
    for (int k0 = 0; k0 < 256; k0 += 64) {
        __syncthreads();
        async_cp16(Ag + k0, Asw);
        #pragma unroll
        for (int c = 0; c < 8; c++)
            async_cp16(Bg + (size_t)c * 8 * 256 + k0, Bsw + c * 8 * 64);
        __syncthreads();
        #pragma unroll
        for (int kk = 0; kk < 64; kk += 32) {
            const int slot = (((kk >> 3) + q) ^ sw) * 8;
            short8v af = *(const short8v*)&As[(wm + fm) * 64 + slot];
            #pragma unroll
            for (int ni = 0; ni < 8; ni++) {
                short8v bf = *(const short8v*)&Bs[(wn + ni * 16 + fm) * 64 + slot];
                acc[ni] = __builtin_amdgcn_mfma_f32_16x16x32_bf16(bf, af, acc[ni], 0, 0, 0);
            }
        }
    }

    // epilogue: row m = m0+wm+fm; thread covers 32 of its 256 channels
    int m = m0 + wm + fm;
    float v[8][4];
    float s = 0.f, sq = 0.f;
    #pragma unroll
    for (int ni = 0; ni < 8; ni++) {
        int nb = wn + ni * 16 + q * 4;
        float4 xv = *(const float4*)(x + (size_t)m * 256 + nb);
        float4 bv = *(const float4*)&bps[nb];
        #pragma unroll
        for (int r = 0; r < 4; r++) {
            float t = acc[ni][r] + (&bv.x)[r] + (&xv.x)[r];
            v[ni][r] = t;
            s += t; sq += t * t;
        }
    }
    s += __shfl_xor(s, 16);  s += __shfl_xor(s, 32);   // sum over q -> 128 ch
    sq += __shfl_xor(sq, 16); sq += __shfl_xor(sq, 32);
    if (q == 0) { ps[w][fm] = s; pq[w][fm] = sq; }
    __syncthreads();
    s = ps[w][fm] + ps[w ^ 2][fm];                      // + partner wave's 128 ch
    sq = pq[w][fm] + pq[w ^ 2][fm];
    float mu = s * 0.00390625f;
    float rs = rsqrtf(sq * 0.00390625f - mu * mu + 1e-5f);
    #pragma unroll
    for (int ni = 0; ni < 8; ni++) {
        int nb = wn + ni * 16 + q * 4;
        size_t idx = (size_t)m * 256 + nb;
        float4 gv = *(const float4*)&gs[nb];
        float4 bv = *(const float4*)&bs[nb];
        uint2 xo, ho;
        xo.x = (u32)f2b(v[ni][0]) | ((u32)f2b(v[ni][1]) << 16);
        xo.y = (u32)f2b(v[ni][2]) | ((u32)f2b(v[ni][3]) << 16);
        float h0 = (v[ni][0] - mu) * rs * gv.x + bv.x;
        float h1 = (v[ni][1] - mu) * rs * gv.y + bv.y;
        float h2v = (v[ni][2] - mu) * rs * gv.z + bv.z;
        float h3 = (v[ni][3] - mu) * rs * gv.w + bv.w;
        ho.x = (u32)f2b(h0) | ((u32)f2b(h1) << 16);
        ho.y = (u32)f2b(h2v) | ((u32)f2b(h3) << 16);
        *(uint2*)&x2b[idx] = xo;
        *(uint2*)&h2[idx] = ho;    // in-place over att: own rows, post-k-loop
    }
}

// ---------------- MFMA flash attention: single sweep, dual q-tile -----------
__global__ __launch_bounds__(256) void attn_mfma(const u16* __restrict__ qk,
                                                 const u16* __restrict__ vtg,
                                                 u16* __restrict__ att) {
    const int T = 1024;
    int jj = (blockIdx.x + (blockIdx.y >> 3)) & 7;
    int b = blockIdx.y >> 3, hh = blockIdx.y & 7;
    int tid = threadIdx.x;
    int lane = tid & 63, w = tid >> 6;
    int fm = lane & 15, q = lane >> 4;

    __shared__ __align__(16) u16 Ks[64][72];
    __shared__ __align__(16) u16 Vt[32][72];
    __shared__ __align__(16) u16 Pl[4][16][72];

    size_t base = (size_t)b * T * 512;
    const u16* kb = qk + base + 256 + hh * 32;
    const u16* vt = vtg + (size_t)((b * 8 + hh) * 32) * 1024;
    const int krow = tid >> 2, kcol = (tid & 3) * 8;
    const int vd = tid >> 3, vs = (tid & 7) * 8;

    int qa0 = jj * 64, qb0 = (15 - jj) * 64;
    int tqa = qa0 + w * 16 + fm, tqb = qb0 + w * 16 + fm;
    short8v qfa = *(const short8v*)(qk + base + (size_t)tqa * 512 + hh * 32 + q * 8);
    short8v qfb = *(const short8v*)(qk + base + (size_t)tqb * 512 + hh * 32 + q * 8);
    float4v oa0 = {0.f, 0.f, 0.f, 0.f}, oa1 = {0.f, 0.f, 0.f, 0.f};
    float4v ob0 = {0.f, 0.f, 0.f, 0.f}, ob1 = {0.f, 0.f, 0.f, 0.f};
    float la = 0.f, lb = 0.f;
    int wqa = qa0 + w * 16, wqb = qb0 + w * 16;
    int nIter = 16 - jj;

    uint4 kreg = *(const uint4*)(kb + (size_t)krow * 512 + kcol);
    uint4 vreg = *(const uint4*)(vt + (size_t)vd * 1024 + vs);

    for (int it = 0; it < nIter; ++it) {
        int s0 = it << 6;
        __syncthreads();
        *(uint4*)&Ks[krow][kcol] = kreg;
        *(uint4*)&Vt[vd][vs] = vreg;
        __syncthreads();
        if (it + 1 < nIter) {
            int ns0 = s0 + 64;
            kreg = *(const uint4*)(kb + (size_t)(ns0 + krow) * 512 + kcol);
            vreg = *(const uint4*)(vt + (size_t)vd * 1024 + ns0 + vs);
        }
        short8v kf0 = *(const short8v*)&Ks[fm][q * 8];
        short8v kf1 = *(const short8v*)&Ks[16 + fm][q * 8];
        short8v kf2 = *(const short8v*)&Ks[32 + fm][q * 8];
        short8v kf3 = *(const short8v*)&Ks[48 + fm][q * 8];
        short8v vf00 = *(const short8v*)&Vt[fm][q * 8];
        short8v vf01 = *(const short8v*)&Vt[fm][32 + q * 8];
        short8v vf10 = *(const short8v*)&Vt[16 + fm][q * 8];
        short8v vf11 = *(const short8v*)&Vt[16 + fm][32 + q * 8];
        float4v z = {0.f, 0.f, 0.f, 0.f};

        #pragma unroll
        for (int t2 = 0; t2 < 2; t2++) {       // t2=0: tile b (large), 1: tile a
            int wq0 = t2 ? wqa : wqb;
            if (s0 >= wq0 + 16) continue;      // wave-uniform causal skip
            int tq = t2 ? tqa : tqb;
            short8v qf = t2 ? qfa : qfb;
            float4v s_0 = __builtin_amdgcn_mfma_f32_16x16x32_bf16(kf0, qf, z, 0, 0, 0);
            float4v s_1 = __builtin_amdgcn_mfma_f32_16x16x32_bf16(kf1, qf, z, 0, 0, 0);
            float4v s_2 = __builtin_amdgcn_mfma_f32_16x16x32_bf16(kf2, qf, z, 0, 0, 0);
            float4v s_3 = __builtin_amdgcn_mfma_f32_16x16x32_bf16(kf3, qf, z, 0, 0, 0);
            float p[16];
            #pragma unroll
            for (int r = 0; r < 4; r++) {
                p[r] = exp2f(s_0[r]); p[4 + r] = exp2f(s_1[r]);
                p[8 + r] = exp2f(s_2[r]); p[12 + r] = exp2f(s_3[r]);
            }
            if (s0 + 63 > wq0) {               // diagonal region: causal mask
                int sb = s0 + q * 4;
                #pragma unroll
                for (int c = 0; c < 4; c++)
                    #pragma unroll
                    for (int r = 0; r < 4; r++)
                        if (sb + c * 16 + r > tq) p[c * 4 + r] = 0.f;
            }
            float rsum = 0.f;
            #pragma unroll
            for (int i = 0; i < 16; i++) rsum += p[i];
            rsum += __shfl_xor(rsum, 16);
            rsum += __shfl_xor(rsum, 32);
            if (t2) la += rsum; else lb += rsum;

            #pragma unroll
            for (int c = 0; c < 4; c++) {
                uint2 pp;
                pp.x = pk2_rtz(p[c * 4 + 0], p[c * 4 + 1]);
                pp.y = pk2_rtz(p[c * 4 + 2], p[c * 4 + 3]);
                *(uint2*)&Pl[w][fm][c * 16 + q * 4] = pp;   // wave-internal
            }
            short8v pf0 = *(const short8v*)&Pl[w][fm][q * 8];
            short8v pf1 = *(const short8v*)&Pl[w][fm][32 + q * 8];
            if (t2) {
                oa0 = __builtin_amdgcn_mfma_f32_16x16x32_bf16(vf00, pf0, oa0, 0, 0, 0);
                oa0 = __builtin_amdgcn_mfma_f32_16x16x32_bf16(vf01, pf1, oa0, 0, 0, 0);
                oa1 = __builtin_amdgcn_mfma_f32_16x16x32_bf16(vf10, pf0, oa1, 0, 0, 0);
                oa1 = __builtin_amdgcn_mfma_f32_16x16x32_bf16(vf11, pf1, oa1, 0, 0, 0);
            } else {
                ob0 = __builtin_amdgcn_mfma_f32_16x16x32_bf16(vf00, pf0, ob0, 0, 0, 0);
                ob0 = __builtin_amdgcn_mfma_f32_16x16x32_bf16(vf01, pf1, ob0, 0, 0, 0);
                ob1 = __builtin_amdgcn_mfma_f32_16x16x32_bf16(vf10, pf0, ob1, 0, 0, 0);
                ob1 = __builtin_amdgcn_mfma_f32_16x16x32_bf16(vf11, pf1, ob1, 0, 0, 0);
            }
        }
    }

    #pragma unroll
    for (int t2 = 0; t2 < 2; t2++) {
        float inv = 1.f / (t2 ? la : lb);
        float4v o0 = t2 ? oa0 : ob0, o1 = t2 ? oa1 : ob1;
        int tq = t2 ? tqa : tqb;
        uint2 r0, r1;
        r0.x = (u32)f2b(o0[0] * inv) | ((u32)f2b(o0[1] * inv) << 16);
        r0.y = (u32)f2b(o0[2] * inv) | ((u32)f2b(o0[3] * inv) << 16);
        r1.x = (u32)f2b(o1[0] * inv) | ((u32)f2b(o1[1] * inv) << 16);
        r1.y = (u32)f2b(o1[2] * inv) | ((u32)f2b(o1[3] * inv) << 16);
        size_t o = (size_t)(b * T + tq) * 256 + hh * 32;
        *(uint2*)(att + o + q * 4) = r0;
        *(uint2*)(att + o + 16 + q * 4) = r1;
    }
}

// ---------------- launch ----------------
extern "C" void kernel_launch(void* const* d_in, const int* in_sizes, int n_in,
                              void* d_out, int out_size, void* d_ws, size_t ws_size,
                              hipStream_t stream) {
    const int BT = 16 * 1024;
    const float* x      = (const float*)d_in[0];
    const float* wq     = (const float*)d_in[1];
    const float* wk     = (const float*)d_in[2];
    const float* wv     = (const float*)d_in[3];
    const float* w_proj = (const float*)d_in[4];
    const float* b_proj = (const float*)d_in[5];
    const float* w1     = (const float*)d_in[6];
    const float* b1     = (const float*)d_in[7];
    const float* w2     = (const float*)d_in[8];
    const float* b2     = (const float*)d_in[9];
    const float* ln1_g  = (const float*)d_in[10];
    const float* ln1_b  = (const float*)d_in[11];
    const float* ln2_g  = (const float*)d_in[12];
    const float* ln2_b  = (const float*)d_in[13];

    // Workspace (~49.5 MiB):
    //   [0, 8M)   x2b (bf16 x2)
    //   [8M,16M)  hbuf: h -> att -> h2  [serial, proj_ln2 in-place]
    //   [16M,32M) qk [BT,512] | [32M,48M) vtg  -> dead after attn
    //   [48M...)  packed weights (1.5M)
    char* ws = (char*)d_ws;
    const size_t MB = 1024 * 1024;
    u16*  x2b   = (u16*)(ws + 0);
    u16*  hbuf  = (u16*)(ws + 8 * MB);
    u16*  qk    = (u16*)(ws + 16 * MB);
    u16*  vtg   = (u16*)(ws + 32 * MB);
    u16*  wqkvT = (u16*)(ws + 48 * MB);
    u16*  wpT   = (u16*)(ws + 48 * MB + 0x60000);
    u16*  w1T   = (u16*)(ws + 48 * MB + 0x80000);
    u16*  w2T   = (u16*)(ws + 48 * MB + 0x100000);

    prep_ln1<<<5008, 256, 0, stream>>>(wq, wk, wv, w_proj, w1, w2, x, ln1_g, ln1_b,
                                       wqkvT, wpT, w1T, w2T, hbuf);
    // qk | vtg = h @ [Wq'|Wk|Wv]
    gemm128<false, false, true><<<dim3(128, 6), 256, 0, stream>>>(
        hbuf, wqkvT, nullptr, qk, vtg, BT, 512, 256);
    // att = flash attention (writes over h)
    attn_mfma<<<dim3(8, 128), 256, 0, stream>>>(qk, vtg, hbuf);
    // x2 = x + att @ w_proj + b_proj ; h2 = LN2(x2)  [32-row blocks, 2/CU]
    proj_ln2<<<512, 256, 0, stream>>>(hbuf, wpT, b_proj, x, ln2_g, ln2_b, x2b, hbuf);
    // out = x2 + relu(h2 @ w1 + b1) @ w2 + b2  [A-in-regs, 3-buf B, 1 barrier/tile]
    ffn_fused<<<256, 512, 0, stream>>>(hbuf, w1T, b1, w2T, b2, x2b, (float*)d_out);
}

// Round 5
// 178.485 us; speedup vs baseline: 1.0570x; 1.0013x over previous
//
#include <hip/hip_runtime.h>

// EncoderBlock on MI355X. Round 19: counted-vmcnt double-buffering applied to
// gemm128 (qkv) and proj_ln2 — the two kernels still running the old
// stage -> drain-barrier structure. Per K-step: s_waitcnt vmcnt(8|9) ->
// s_barrier -> compute -> s_barrier -> issue step t+2. vmcnt(0) only at the
// last step. proj_ln2 drops gs/bs/bps LDS staging (would inject compiler
// vmcnt waits); epilogue reads bias/gamma/beta straight from L2.
// ffn_fused/attn/prep identical to r18 (178.7 µs). B=16 T=1024 C=256 H=8 D=32.

typedef unsigned short u16;
typedef unsigned int u32;
typedef __attribute__((ext_vector_type(8))) short short8v;  // 8 bf16 MFMA A/B frag
typedef __attribute__((ext_vector_type(4))) float float4v;  // MFMA C/D frag

__device__ __forceinline__ float b2f(u16 u) { union { u32 i; float f; } v; v.i = (u32)u << 16; return v.f; }
__device__ __forceinline__ float lo2f(u32 u) { union { u32 i; float f; } v; v.i = u << 16; return v.f; }
__device__ __forceinline__ float hi2f(u32 u) { union { u32 i; float f; } v; v.i = u & 0xffff0000u; return v.f; }
__device__ __forceinline__ u16 f2b(float f) {
    union { float f; u32 i; } v; v.f = f;
    u32 r = v.i + 0x7fffu + ((v.i >> 16) & 1u);  // RTNE
    return (u16)(r >> 16);
}
__device__ __forceinline__ u32 pk2_rtz(float a, float b) {
    return (__float_as_uint(a) >> 16) | (__float_as_uint(b) & 0xffff0000u);
}
__device__ __forceinline__ void async_cp16(const u16* g, u16* l) {
    __builtin_amdgcn_global_load_lds((const __attribute__((address_space(1))) void*)g,
                                     (__attribute__((address_space(3))) void*)l, 16, 0, 0);
}

// ---------------- fused prep (wqkv pack + 3 transposes) + LN1 ---------------
__global__ __launch_bounds__(256) void prep_ln1(const float* __restrict__ wq,
                                                const float* __restrict__ wk,
                                                const float* __restrict__ wv,
                                                const float* __restrict__ wp,
                                                const float* __restrict__ w1,
                                                const float* __restrict__ w2,
                                                const float* __restrict__ x,
                                                const float* __restrict__ g1,
                                                const float* __restrict__ be1,
                                                u16* __restrict__ wqkvT,
                                                u16* __restrict__ wpT,
                                                u16* __restrict__ w1T,
                                                u16* __restrict__ w2T,
                                                u16* __restrict__ hout) {
    __shared__ u16 tile[64][65];
    int bid = blockIdx.x, tid = threadIdx.x;
    if (bid < 768) {
        int i = bid * 256 + tid;
        int n = i >> 8, k = i & 255;
        int which = n >> 8, nn = n & 255;
        const float* w = which == 0 ? wq : (which == 1 ? wk : wv);
        float v = w[((nn >> 5) * 256 + k) * 32 + (nn & 31)];   // w[h][k][d]
        if (which == 0) v *= 0.09016844f;                      // (1/16)*log2(e)
        wqkvT[i] = f2b(v);
    } else if (bid < 912) {
        const float* src; u16* dst; int K, N, t;
        if (bid < 784)      { src = wp; dst = wpT; K = 256;  N = 256;  t = bid - 768; }
        else if (bid < 848) { src = w1; dst = w1T; K = 256;  N = 1024; t = bid - 784; }
        else                { src = w2; dst = w2T; K = 1024; N = 256;  t = bid - 848; }
        int ntn = N >> 6;
        int k0 = (t / ntn) << 6, n0 = (t % ntn) << 6;
        int lane = tid & 63, wrow = tid >> 6;
        #pragma unroll
        for (int r = 0; r < 16; r++) {
            int k = wrow * 16 + r;
            tile[k][lane] = f2b(src[(size_t)(k0 + k) * N + n0 + lane]);
        }
        __syncthreads();
        #pragma unroll
        for (int r = 0; r < 16; r++) {
            int n = wrow * 16 + r;
            dst[(size_t)(n0 + n) * K + k0 + lane] = tile[lane][n];
        }
    } else {
        int row = (bid - 912) * 4 + (tid >> 6);
        int lane = tid & 63;
        float4 xv = *(const float4*)(x + (size_t)row * 256 + lane * 4);
        float v0 = xv.x, v1 = xv.y, v2 = xv.z, v3 = xv.w;
        float s = v0 + v1 + v2 + v3;
        #pragma unroll
        for (int m = 32; m; m >>= 1) s += __shfl_xor(s, m);
        float mu = s * 0.00390625f;
        float d0 = v0 - mu, d1 = v1 - mu, d2 = v2 - mu, d3 = v3 - mu;
        float ss = d0 * d0 + d1 * d1 + d2 * d2 + d3 * d3;
        #pragma unroll
        for (int m = 32; m; m >>= 1) ss += __shfl_xor(ss, m);
        float rs = rsqrtf(ss * 0.00390625f + 1e-5f);
        float4 g = *(const float4*)(g1 + lane * 4);
        float4 b = *(const float4*)(be1 + lane * 4);
        uint2 r;
        r.x = (u32)f2b(d0 * rs * g.x + b.x) | ((u32)f2b(d1 * rs * g.y + b.y) << 16);
        r.y = (u32)f2b(d2 * rs * g.z + b.z) | ((u32)f2b(d3 * rs * g.w + b.w) << 16);
        *(uint2*)(hout + (size_t)row * 256 + lane * 4) = r;
    }
}

// ---------------- 128x128 MFMA GEMM (qkv): counted-vmcnt double buffer ------
// K must be 256 (4 fully-unrolled steps). LDS 64KB = 2 x (As 16K | Bs 16K);
// V-transpose reuses the same 64KB after a syncthreads.
template<bool HASBIAS, bool RELU, bool QKV>
__global__ __launch_bounds__(256) void gemm128(const u16* __restrict__ A,
                                               const u16* __restrict__ Bt,
                                               const float* __restrict__ bias,
                                               u16* __restrict__ out,
                                               u16* __restrict__ vout,
                                               int M, int N, int K) {
    __shared__ __align__(16) u16 SH[32768];      // 64KB
    const int tid = threadIdx.x, lane = tid & 63, w = tid >> 6;
    const int m0 = blockIdx.x * 128, n0 = blockIdx.y * 128;
    const int wm = (w & 1) * 64, wn = (w >> 1) * 64;
    const int fm = lane & 15, q = lane >> 4;

    float4v acc[4][4];
    #pragma unroll
    for (int i = 0; i < 4; i++)
        #pragma unroll
        for (int j = 0; j < 4; j++) acc[i][j] = (float4v){0.f, 0.f, 0.f, 0.f};

    const int kset = ((lane & 7) ^ (lane >> 3)) * 8;
    const u16* Ag = A  + (size_t)(m0 + w * 32 + (lane >> 3)) * K + kset;
    const u16* Bg = Bt + (size_t)(n0 + w * 32 + (lane >> 3)) * K + kset;

    // stage step t (k0 = t*64) into buffer d: 8 vmcnt ops per wave
    auto issueS = [&](int t, int d) {
        u16* Asw = SH + d * 16384 + (w * 32) * 64;
        u16* Bsw = SH + d * 16384 + 8192 + (w * 32) * 64;
        #pragma unroll
        for (int c = 0; c < 4; c++) {
            async_cp16(Ag + (size_t)c * 8 * K + t * 64, Asw + c * 8 * 64);
            async_cp16(Bg + (size_t)c * 8 * K + t * 64, Bsw + c * 8 * 64);
        }
    };
    issueS(0, 0);
    issueS(1, 1);

    const int sw = fm & 7;
    #pragma unroll
    for (int t = 0; t < 4; ++t) {
        // step t landed; step t+1 (8 ops) stays in flight across the barrier
        if (t == 3) asm volatile("s_waitcnt vmcnt(0)" ::: "memory");
        else        asm volatile("s_waitcnt vmcnt(8)" ::: "memory");
        __builtin_amdgcn_s_barrier();
        const u16* As = SH + (t & 1) * 16384;
        const u16* Bs = As + 8192;
        #pragma unroll
        for (int kk = 0; kk < 64; kk += 32) {
            const int slot = (((kk >> 3) + q) ^ sw) * 8;
            short8v af[4], bf[4];
            #pragma unroll
            for (int mi = 0; mi < 4; mi++)
                af[mi] = *(const short8v*)&As[(wm + mi * 16 + fm) * 64 + slot];
            #pragma unroll
            for (int ni = 0; ni < 4; ni++)
                bf[ni] = *(const short8v*)&Bs[(wn + ni * 16 + fm) * 64 + slot];
            #pragma unroll
            for (int mi = 0; mi < 4; mi++)
                #pragma unroll
                for (int ni = 0; ni < 4; ni++)
                    acc[mi][ni] = __builtin_amdgcn_mfma_f32_16x16x32_bf16(
                        bf[ni], af[mi], acc[mi][ni], 0, 0, 0);
        }
        if (t < 2) {
            // all waves done reading buf(t&1) -> safe to overwrite with S(t+2)
            __builtin_amdgcn_s_barrier();
            issueS(t + 2, t & 1);
        }
    }

    if (QKV && n0 >= 512) {
        // V tile: transpose via LDS, then coalesced full-line stores.
        __syncthreads();
        #pragma unroll
        for (int mi = 0; mi < 4; mi++) {
            int ml = wm + mi * 16 + fm;
            #pragma unroll
            for (int ni = 0; ni < 4; ni++) {
                int nl = wn + ni * 16 + q * 4;
                #pragma unroll
                for (int r = 0; r < 4; r++)
                    SH[(nl + r) * 136 + ml] = f2b(acc[mi][ni][r]);
            }
        }
        __syncthreads();
        int r = tid & 127, c = (tid >> 7) << 6;
        int hd = (n0 - 512) + r;
        int b = m0 >> 10, t0 = m0 & 1023;
        u16* dst = vout + (size_t)(b * 256 + hd) * 1024 + t0 + c;
        const u16* srcT = SH + r * 136 + c;
        #pragma unroll
        for (int i = 0; i < 8; i++)
            *(uint4*)(dst + i * 8) = *(const uint4*)(srcT + i * 8);
        return;
    }

    #pragma unroll
    for (int mi = 0; mi < 4; mi++) {
        int row = m0 + wm + mi * 16 + fm;
        #pragma unroll
        for (int ni = 0; ni < 4; ni++) {
            int nb = n0 + wn + ni * 16 + q * 4;
            float v0 = acc[mi][ni][0], v1 = acc[mi][ni][1],
                  v2 = acc[mi][ni][2], v3 = acc[mi][ni][3];
            if (HASBIAS) {
                float4 bv = *(const float4*)&bias[nb];
                v0 += bv.x; v1 += bv.y; v2 += bv.z; v3 += bv.w;
            }
            if (RELU) {
                v0 = fmaxf(v0, 0.f); v1 = fmaxf(v1, 0.f);
                v2 = fmaxf(v2, 0.f); v3 = fmaxf(v3, 0.f);
            }
            size_t idx = (size_t)row * N + nb;
            uint2 ov;
            ov.x = (u32)f2b(v0) | ((u32)f2b(v1) << 16);
            ov.y = (u32)f2b(v2) | ((u32)f2b(v3) << 16);
            *(uint2*)&out[idx] = ov;
        }
    }
}

// ---------------- fused FFN: out = x2 + relu(h2@w1+b1)@w2 + b2 --------------
// 64-row blocks, 512 threads (8 waves = 2m x 4n), grid 256 = 1 block/CU.
// A-tile in registers (16 short8v/thread). mid strip in LDS (Ms). B-tiles
// triple-buffered; per tile: s_waitcnt vmcnt(4) -> s_barrier -> issue B(t+2)
// into buf (t+2)%3 (= buf read at t-1, safe) -> compute. Fully unrolled.
// lgkmcnt(0) only after the 4 Ms-write tiles. LDS 128KB: Ms 32K | Bs 3x32K.
__global__ __launch_bounds__(512, 2) void ffn_fused(const u16* __restrict__ h2,
                                                    const u16* __restrict__ w1T,
                                                    const float* __restrict__ b1,
                                                    const u16* __restrict__ w2T,
                                                    const float* __restrict__ b2,
                                                    const u16* __restrict__ x2b,
                                                    float* __restrict__ out) {
    __shared__ __align__(16) u16 SH[65536];   // 128KB
    u16* Ms = SH;             // [4 kc][64][64] mid chunk, kset-swizzled
    u16* Bs = SH + 16384;     // 3 x [256][64] weight tile (triple buffer)
    const int tid = threadIdx.x, lane = tid & 63, w = tid >> 6;
    const int m0 = blockIdx.x * 64;
    const int wm = (w & 1) * 32;              // m-half (32 rows)
    const int wn = (w >> 1) * 64;             // n-quarter (64 cols)
    const int fm = lane & 15, q = lane >> 4;
    const int sw = fm & 7;
    const int kset = ((lane & 7) ^ (lane >> 3)) * 8;
    const int rb = w * 8 + (lane >> 3);       // staging row 0..63

    // ---- A-tile into registers: ar[kcn][mi] = h2[row(mi)][kcn*32 + q*8] ----
    short8v ar[8][2];
    {
        const u16* Abase = h2 + (size_t)(m0 + wm + fm) * 256 + q * 8;
        #pragma unroll
        for (int kcn = 0; kcn < 8; kcn++)
            #pragma unroll
            for (int mi = 0; mi < 2; mi++)
                ar[kcn][mi] = *(const short8v*)(Abase + (size_t)mi * 16 * 256 + kcn * 32);
    }

    // ---- B-tile issue helper (4 async_cp16 = 4 vmcnt ops per wave) ----
    auto issueB = [&](int t, u16* dst) {
        const int n2 = t >> 3, k2 = t & 3;
        if (((t >> 2) & 1) == 0) {
            const u16* src = w1T + (size_t)(n2 * 256 + rb) * 256 + k2 * 64 + kset;
            #pragma unroll
            for (int c = 0; c < 4; c++)
                async_cp16(src + (size_t)c * 64 * 256, dst + c * 4096);
        } else {
            const u16* src = w2T + (size_t)rb * 1024 + n2 * 256 + k2 * 64 + kset;
            #pragma unroll
            for (int c = 0; c < 4; c++)
                async_cp16(src + (size_t)c * 64 * 1024, dst + c * 4096);
        }
    };

    // ---- prologue: B tiles 0,1 (8 vm ops after the 16 A-loads) ----
    issueB(0, Bs + w * 512);
    issueB(1, Bs + 16384 + w * 512);

    float4v acc1[2][4], acc2[2][4];
    #pragma unroll
    for (int i = 0; i < 2; i++)
        #pragma unroll
        for (int j = 0; j < 4; j++) acc2[i][j] = (float4v){0.f, 0.f, 0.f, 0.f};

    #pragma unroll
    for (int t = 0; t < 32; ++t) {
        const int nch = t >> 3, ph = (t >> 2) & 1, kc = t & 3;
        // B(t) landed; B(t+1) stays in flight (4 ops). Also drains A at t=0.
        if (t == 31) asm volatile("s_waitcnt vmcnt(0)" ::: "memory");
        else         asm volatile("s_waitcnt vmcnt(4)" ::: "memory");
        __builtin_amdgcn_s_barrier();
        // issue B(t+2) into buf (t+2)%3 == buf read at t-1 (all done by barrier)
        if (t + 2 < 32)
            issueB(t + 2, Bs + ((t + 2) % 3) * 16384 + w * 512);
        const u16* Bb = Bs + (t % 3) * 16384;
        if (ph == 0) {
            if (kc == 0) {
                #pragma unroll
                for (int i = 0; i < 2; i++)
                    #pragma unroll
                    for (int j = 0; j < 4; j++) acc1[i][j] = (float4v){0.f, 0.f, 0.f, 0.f};
            }
            #pragma unroll
            for (int kk = 0; kk < 64; kk += 32) {
                const int slot = (((kk >> 3) + q) ^ sw) * 8;
                short8v bf[4];
                #pragma unroll
                for (int ni = 0; ni < 4; ni++)
                    bf[ni] = *(const short8v*)&Bb[(wn + ni * 16 + fm) * 64 + slot];
                #pragma unroll
                for (int mi = 0; mi < 2; mi++)
                    #pragma unroll
                    for (int ni = 0; ni < 4; ni++)
                        acc1[mi][ni] = __builtin_amdgcn_mfma_f32_16x16x32_bf16(
                            bf[ni], ar[kc * 2 + (kk >> 5)][mi], acc1[mi][ni], 0, 0, 0);
            }
            if (kc == 3) {
                // bias + relu -> Ms (swizzled A layout for gemm2)
                #pragma unroll
                for (int ni = 0; ni < 4; ni++) {
                    const int c2 = wn + ni * 16 + q * 4;       // 0..255
                    const int kcM = c2 >> 6, cc = c2 & 63;
                    float4 bv = *(const float4*)&b1[nch * 256 + c2];
                    #pragma unroll
                    for (int mi = 0; mi < 2; mi++) {
                        const int row = wm + mi * 16 + fm;
                        float v0 = fmaxf(acc1[mi][ni][0] + bv.x, 0.f);
                        float v1 = fmaxf(acc1[mi][ni][1] + bv.y, 0.f);
                        float v2 = fmaxf(acc1[mi][ni][2] + bv.z, 0.f);
                        float v3 = fmaxf(acc1[mi][ni][3] + bv.w, 0.f);
                        uint2 pp;
                        pp.x = (u32)f2b(v0) | ((u32)f2b(v1) << 16);
                        pp.y = (u32)f2b(v2) | ((u32)f2b(v3) << 16);
                        *(uint2*)&Ms[kcM * 4096 + row * 64 +
                                     (((cc >> 3) ^ (row & 7)) * 8) + (cc & 7)] = pp;
                    }
                }
                // publish Ms before next barrier (cross-wave read at t+1)
                asm volatile("s_waitcnt lgkmcnt(0)" ::: "memory");
            }
        } else {
            const u16* Ab = Ms + kc * 4096;
            #pragma unroll
            for (int kk = 0; kk < 64; kk += 32) {
                const int slot = (((kk >> 3) + q) ^ sw) * 8;
                short8v af[2], bf[4];
                #pragma unroll
                for (int mi = 0; mi < 2; mi++)
                    af[mi] = *(const short8v*)&Ab[(wm + mi * 16 + fm) * 64 + slot];
                #pragma unroll
                for (int ni = 0; ni < 4; ni++)
                    bf[ni] = *(const short8v*)&Bb[(wn + ni * 16 + fm) * 64 + slot];
                #pragma unroll
                for (int mi = 0; mi < 2; mi++)
                    #pragma unroll
                    for (int ni = 0; ni < 4; ni++)
                        acc2[mi][ni] = __builtin_amdgcn_mfma_f32_16x16x32_bf16(
                            bf[ni], af[mi], acc2[mi][ni], 0, 0, 0);
            }
        }
    }

    // ---- epilogue: out = acc2 + b2 + x2 (bf16 resid), fp32 stores ----
    #pragma unroll
    for (int mi = 0; mi < 2; mi++) {
        const int row = m0 + wm + mi * 16 + fm;
        #pragma unroll
        for (int ni = 0; ni < 4; ni++) {
            const int nb = wn + ni * 16 + q * 4;
            size_t idx = (size_t)row * 256 + nb;
            float4 bv = *(const float4*)&b2[nb];
            uint2 rv = *(const uint2*)&x2b[idx];
            float v0 = acc2[mi][ni][0] + bv.x + lo2f(rv.x);
            float v1 = acc2[mi][ni][1] + bv.y + hi2f(rv.x);
            float v2 = acc2[mi][ni][2] + bv.z + lo2f(rv.y);
            float v3 = acc2[mi][ni][3] + bv.w + hi2f(rv.y);
            *(float4*)&out[idx] = (float4){v0, v1, v2, v3};
        }
    }
}

// ---------------- proj GEMM + residual + LN2: counted-vmcnt dbuf ------------
// x2 = att @ wpT^T + bp + x ; h2 = LN2(x2). grid 512, 2 blocks/CU.
// LDS 72KB = 2 x (As 4K | Bs 32K). Per step: vmcnt(9|0) -> barrier ->
// compute -> barrier -> issue t+2. Bias/gamma/beta read direct from L2.
__global__ __launch_bounds__(256) void proj_ln2(const u16* __restrict__ att,
                                                const u16* __restrict__ wpT,
                                                const float* __restrict__ bp,
                                                const float* __restrict__ x,
                                                const float* __restrict__ g2,
                                                const float* __restrict__ be2,
                                                u16* __restrict__ x2b,
                                                u16* __restrict__ h2) {
    __shared__ __align__(16) u16 AB[2][18432];   // per buf: As 2048 | Bs 16384
    __shared__ float ps[4][16], pq[4][16];
    const int tid = threadIdx.x, lane = tid & 63, w = tid >> 6;
    const int m0 = blockIdx.x * 32;
    const int wm = (w & 1) * 16, wn = (w >> 1) * 128;
    const int fm = lane & 15, q = lane >> 4;

    float4v acc[8];
    #pragma unroll
    for (int i = 0; i < 8; i++) acc[i] = (float4v){0.f, 0.f, 0.f, 0.f};

    const int kset = ((lane & 7) ^ (lane >> 3)) * 8;
    const u16* Ag = att + (size_t)(m0 + w * 8 + (lane >> 3)) * 256 + kset;
    const u16* Bg = wpT + (size_t)(w * 64 + (lane >> 3)) * 256 + kset;

    // stage step t (k0 = t*64) into buffer d: 9 vmcnt ops per wave
    auto issueS = [&](int t, int d) {
        u16* Asw = AB[d] + (w * 8) * 64;
        u16* Bsw = AB[d] + 2048 + (w * 64) * 64;
        async_cp16(Ag + t * 64, Asw);
        #pragma unroll
        for (int c = 0; c < 8; c++)
            async_cp16(Bg + (size_t)c * 8 * 256 + t * 64, Bsw + c * 8 * 64);
    };
    issueS(0, 0);
    issueS(1, 1);

    const int sw = fm & 7;
    #pragma unroll
    for (int t = 0; t < 4; ++t) {
        if (t == 3) asm volatile("s_waitcnt vmcnt(0)" ::: "memory");
        else        asm volatile("s_waitcnt vmcnt(9)" ::: "memory");
        __builtin_amdgcn_s_barrier();
        const u16* As = AB[t & 1];
        const u16* Bs = AB[t & 1] + 2048;
        #pragma unroll
        for (int kk = 0; kk < 64; kk += 32) {
            const int slot = (((kk >> 3) + q) ^ sw) * 8;
            short8v af = *(const short8v*)&As[(wm + fm) * 64 + slot];
            #pragma unroll
            for (int ni = 0; ni < 8; ni++) {
                short8v bf = *(const short8v*)&Bs[(wn + ni * 16 + fm) * 64 + slot];
                acc[ni] = __builtin_amdgcn_mfma_f32_16x16x32_bf16(bf, af, acc[ni], 0, 0, 0);
            }
        }
        if (t < 2) {
            __builtin_amdgcn_s_barrier();
            issueS(t + 2, t & 1);
        }
    }

    // epilogue: row m = m0+wm+fm; thread covers 32 of its 256 channels
    int m = m0 + wm + fm;
    float v[8][4];
    float s = 0.f, sq = 0.f;
    #pragma unroll
    for (int ni = 0; ni < 8; ni++) {
        int nb = wn + ni * 16 + q * 4;
        float4 xv = *(const float4*)(x + (size_t)m * 256 + nb);
        float4 bv = *(const float4*)&bp[nb];
        #pragma unroll
        for (int r = 0; r < 4; r++) {
            float t = acc[ni][r] + (&bv.x)[r] + (&xv.x)[r];
            v[ni][r] = t;
            s += t; sq += t * t;
        }
    }
    s += __shfl_xor(s, 16);  s += __shfl_xor(s, 32);   // sum over q -> 128 ch
    sq += __shfl_xor(sq, 16); sq += __shfl_xor(sq, 32);
    if (q == 0) { ps[w][fm] = s; pq[w][fm] = sq; }
    __syncthreads();
    s = ps[w][fm] + ps[w ^ 2][fm];                      // + partner wave's 128 ch
    sq = pq[w][fm] + pq[w ^ 2][fm];
    float mu = s * 0.00390625f;
    float rs = rsqrtf(sq * 0.00390625f - mu * mu + 1e-5f);
    #pragma unroll
    for (int ni = 0; ni < 8; ni++) {
        int nb = wn + ni * 16 + q * 4;
        size_t idx = (size_t)m * 256 + nb;
        float4 gv = *(const float4*)&g2[nb];
        float4 bv = *(const float4*)&be2[nb];
        uint2 xo, ho;
        xo.x = (u32)f2b(v[ni][0]) | ((u32)f2b(v[ni][1]) << 16);
        xo.y = (u32)f2b(v[ni][2]) | ((u32)f2b(v[ni][3]) << 16);
        float h0 = (v[ni][0] - mu) * rs * gv.x + bv.x;
        float h1 = (v[ni][1] - mu) * rs * gv.y + bv.y;
        float h2v = (v[ni][2] - mu) * rs * gv.z + bv.z;
        float h3 = (v[ni][3] - mu) * rs * gv.w + bv.w;
        ho.x = (u32)f2b(h0) | ((u32)f2b(h1) << 16);
        ho.y = (u32)f2b(h2v) | ((u32)f2b(h3) << 16);
        *(uint2*)&x2b[idx] = xo;
        *(uint2*)&h2[idx] = ho;    // in-place over att: own rows, post-k-loop
    }
}

// ---------------- MFMA flash attention: single sweep, dual q-tile -----------
__global__ __launch_bounds__(256) void attn_mfma(const u16* __restrict__ qk,
                                                 const u16* __restrict__ vtg,
                                                 u16* __restrict__ att) {
    const int T = 1024;
    int jj = (blockIdx.x + (blockIdx.y >> 3)) & 7;
    int b = blockIdx.y >> 3, hh = blockIdx.y & 7;
    int tid = threadIdx.x;
    int lane = tid & 63, w = tid >> 6;
    int fm = lane & 15, q = lane >> 4;

    __shared__ __align__(16) u16 Ks[64][72];
    __shared__ __align__(16) u16 Vt[32][72];
    __shared__ __align__(16) u16 Pl[4][16][72];

    size_t base = (size_t)b * T * 512;
    const u16* kb = qk + base + 256 + hh * 32;
    const u16* vt = vtg + (size_t)((b * 8 + hh) * 32) * 1024;
    const int krow = tid >> 2, kcol = (tid & 3) * 8;
    const int vd = tid >> 3, vs = (tid & 7) * 8;

    int qa0 = jj * 64, qb0 = (15 - jj) * 64;
    int tqa = qa0 + w * 16 + fm, tqb = qb0 + w * 16 + fm;
    short8v qfa = *(const short8v*)(qk + base + (size_t)tqa * 512 + hh * 32 + q * 8);
    short8v qfb = *(const short8v*)(qk + base + (size_t)tqb * 512 + hh * 32 + q * 8);
    float4v oa0 = {0.f, 0.f, 0.f, 0.f}, oa1 = {0.f, 0.f, 0.f, 0.f};
    float4v ob0 = {0.f, 0.f, 0.f, 0.f}, ob1 = {0.f, 0.f, 0.f, 0.f};
    float la = 0.f, lb = 0.f;
    int wqa = qa0 + w * 16, wqb = qb0 + w * 16;
    int nIter = 16 - jj;

    uint4 kreg = *(const uint4*)(kb + (size_t)krow * 512 + kcol);
    uint4 vreg = *(const uint4*)(vt + (size_t)vd * 1024 + vs);

    for (int it = 0; it < nIter; ++it) {
        int s0 = it << 6;
        __syncthreads();
        *(uint4*)&Ks[krow][kcol] = kreg;
        *(uint4*)&Vt[vd][vs] = vreg;
        __syncthreads();
        if (it + 1 < nIter) {
            int ns0 = s0 + 64;
            kreg = *(const uint4*)(kb + (size_t)(ns0 + krow) * 512 + kcol);
            vreg = *(const uint4*)(vt + (size_t)vd * 1024 + ns0 + vs);
        }
        short8v kf0 = *(const short8v*)&Ks[fm][q * 8];
        short8v kf1 = *(const short8v*)&Ks[16 + fm][q * 8];
        short8v kf2 = *(const short8v*)&Ks[32 + fm][q * 8];
        short8v kf3 = *(const short8v*)&Ks[48 + fm][q * 8];
        short8v vf00 = *(const short8v*)&Vt[fm][q * 8];
        short8v vf01 = *(const short8v*)&Vt[fm][32 + q * 8];
        short8v vf10 = *(const short8v*)&Vt[16 + fm][q * 8];
        short8v vf11 = *(const short8v*)&Vt[16 + fm][32 + q * 8];
        float4v z = {0.f, 0.f, 0.f, 0.f};

        #pragma unroll
        for (int t2 = 0; t2 < 2; t2++) {       // t2=0: tile b (large), 1: tile a
            int wq0 = t2 ? wqa : wqb;
            if (s0 >= wq0 + 16) continue;      // wave-uniform causal skip
            int tq = t2 ? tqa : tqb;
            short8v qf = t2 ? qfa : qfb;
            float4v s_0 = __builtin_amdgcn_mfma_f32_16x16x32_bf16(kf0, qf, z, 0, 0, 0);
            float4v s_1 = __builtin_amdgcn_mfma_f32_16x16x32_bf16(kf1, qf, z, 0, 0, 0);
            float4v s_2 = __builtin_amdgcn_mfma_f32_16x16x32_bf16(kf2, qf, z, 0, 0, 0);
            float4v s_3 = __builtin_amdgcn_mfma_f32_16x16x32_bf16(kf3, qf, z, 0, 0, 0);
            float p[16];
            #pragma unroll
            for (int r = 0; r < 4; r++) {
                p[r] = exp2f(s_0[r]); p[4 + r] = exp2f(s_1[r]);
                p[8 + r] = exp2f(s_2[r]); p[12 + r] = exp2f(s_3[r]);
            }
            if (s0 + 63 > wq0) {               // diagonal region: causal mask
                int sb = s0 + q * 4;
                #pragma unroll
                for (int c = 0; c < 4; c++)
                    #pragma unroll
                    for (int r = 0; r < 4; r++)
                        if (sb + c * 16 + r > tq) p[c * 4 + r] = 0.f;
            }
            float rsum = 0.f;
            #pragma unroll
            for (int i = 0; i < 16; i++) rsum += p[i];
            rsum += __shfl_xor(rsum, 16);
            rsum += __shfl_xor(rsum, 32);
            if (t2) la += rsum; else lb += rsum;

            #pragma unroll
            for (int c = 0; c < 4; c++) {
                uint2 pp;
                pp.x = pk2_rtz(p[c * 4 + 0], p[c * 4 + 1]);
                pp.y = pk2_rtz(p[c * 4 + 2], p[c * 4 + 3]);
                *(uint2*)&Pl[w][fm][c * 16 + q * 4] = pp;   // wave-internal
            }
            short8v pf0 = *(const short8v*)&Pl[w][fm][q * 8];
            short8v pf1 = *(const short8v*)&Pl[w][fm][32 + q * 8];
            if (t2) {
                oa0 = __builtin_amdgcn_mfma_f32_16x16x32_bf16(vf00, pf0, oa0, 0, 0, 0);
                oa0 = __builtin_amdgcn_mfma_f32_16x16x32_bf16(vf01, pf1, oa0, 0, 0, 0);
                oa1 = __builtin_amdgcn_mfma_f32_16x16x32_bf16(vf10, pf0, oa1, 0, 0, 0);
                oa1 = __builtin_amdgcn_mfma_f32_16x16x32_bf16(vf11, pf1, oa1, 0, 0, 0);
            } else {
                ob0 = __builtin_amdgcn_mfma_f32_16x16x32_bf16(vf00, pf0, ob0, 0, 0, 0);
                ob0 = __builtin_amdgcn_mfma_f32_16x16x32_bf16(vf01, pf1, ob0, 0, 0, 0);
                ob1 = __builtin_amdgcn_mfma_f32_16x16x32_bf16(vf10, pf0, ob1, 0, 0, 0);
                ob1 = __builtin_amdgcn_mfma_f32_16x16x32_bf16(vf11, pf1, ob1, 0, 0, 0);
            }
        }
    }

    #pragma unroll
    for (int t2 = 0; t2 < 2; t2++) {
        float inv = 1.f / (t2 ? la : lb);
        float4v o0 = t2 ? oa0 : ob0, o1 = t2 ? oa1 : ob1;
        int tq = t2 ? tqa : tqb;
        uint2 r0, r1;
        r0.x = (u32)f2b(o0[0] * inv) | ((u32)f2b(o0[1] * inv) << 16);
        r0.y = (u32)f2b(o0[2] * inv) | ((u32)f2b(o0[3] * inv) << 16);
        r1.x = (u32)f2b(o1[0] * inv) | ((u32)f2b(o1[1] * inv) << 16);
        r1.y = (u32)f2b(o1[2] * inv) | ((u32)f2b(o1[3] * inv) << 16);
        size_t o = (size_t)(b * T + tq) * 256 + hh * 32;
        *(uint2*)(att + o + q * 4) = r0;
        *(uint2*)(att + o + 16 + q * 4) = r1;
    }
}

// ---------------- launch ----------------
extern "C" void kernel_launch(void* const* d_in, const int* in_sizes, int n_in,
                              void* d_out, int out_size, void* d_ws, size_t ws_size,
                              hipStream_t stream) {
    const int BT = 16 * 1024;
    const float* x      = (const float*)d_in[0];
    const float* wq     = (const float*)d_in[1];
    const float* wk     = (const float*)d_in[2];
    const float* wv     = (const float*)d_in[3];
    const float* w_proj = (const float*)d_in[4];
    const float* b_proj = (const float*)d_in[5];
    const float* w1     = (const float*)d_in[6];
    const float* b1     = (const float*)d_in[7];
    const float* w2     = (const float*)d_in[8];
    const float* b2     = (const float*)d_in[9];
    const float* ln1_g  = (const float*)d_in[10];
    const float* ln1_b  = (const float*)d_in[11];
    const float* ln2_g  = (const float*)d_in[12];
    const float* ln2_b  = (const float*)d_in[13];

    // Workspace (~49.5 MiB):
    //   [0, 8M)   x2b (bf16 x2)
    //   [8M,16M)  hbuf: h -> att -> h2  [serial, proj_ln2 in-place]
    //   [16M,32M) qk [BT,512] | [32M,48M) vtg  -> dead after attn
    //   [48M...)  packed weights (1.5M)
    char* ws = (char*)d_ws;
    const size_t MB = 1024 * 1024;
    u16*  x2b   = (u16*)(ws + 0);
    u16*  hbuf  = (u16*)(ws + 8 * MB);
    u16*  qk    = (u16*)(ws + 16 * MB);
    u16*  vtg   = (u16*)(ws + 32 * MB);
    u16*  wqkvT = (u16*)(ws + 48 * MB);
    u16*  wpT   = (u16*)(ws + 48 * MB + 0x60000);
    u16*  w1T   = (u16*)(ws + 48 * MB + 0x80000);
    u16*  w2T   = (u16*)(ws + 48 * MB + 0x100000);

    prep_ln1<<<5008, 256, 0, stream>>>(wq, wk, wv, w_proj, w1, w2, x, ln1_g, ln1_b,
                                       wqkvT, wpT, w1T, w2T, hbuf);
    // qk | vtg = h @ [Wq'|Wk|Wv]  [counted-vmcnt dbuf]
    gemm128<false, false, true><<<dim3(128, 6), 256, 0, stream>>>(
        hbuf, wqkvT, nullptr, qk, vtg, BT, 512, 256);
    // att = flash attention (writes over h)
    attn_mfma<<<dim3(8, 128), 256, 0, stream>>>(qk, vtg, hbuf);
    // x2 = x + att @ w_proj + b_proj ; h2 = LN2(x2)  [counted-vmcnt dbuf, 2/CU]
    proj_ln2<<<512, 256, 0, stream>>>(hbuf, wpT, b_proj, x, ln2_g, ln2_b, x2b, hbuf);
    // out = x2 + relu(h2 @ w1 + b1) @ w2 + b2  [A-in-regs, 3-buf B, 1 barrier/tile]
    ffn_fused<<<256, 512, 0, stream>>>(hbuf, w1T, b1, w2T, b2, x2b, (float*)d_out);
}

// Round 6
// 176.762 us; speedup vs baseline: 1.0673x; 1.0097x over previous
//
#include <hip/hip_runtime.h>

// EncoderBlock on MI355X. Round 20: tail_fused = proj_ln2 + ffn_fused in ONE
// kernel. Per 64-row strip (grid 256, 512 thr): proj = 4 wpT tiles prepended
// to the counted-vmcnt B-stream (36 tiles total), LN2 as in-register
// interlude (h2 -> Ms-region LDS -> ar regs), x2 stays in fp32 registers to
// the end. h2/x2b never touch global (-32 MB), one fewer launch. 4 launches.
// prep/qkv/attn identical to r19 (178.5 µs). B=16 T=1024 C=256 H=8 D=32.

typedef unsigned short u16;
typedef unsigned int u32;
typedef __attribute__((ext_vector_type(8))) short short8v;  // 8 bf16 MFMA A/B frag
typedef __attribute__((ext_vector_type(4))) float float4v;  // MFMA C/D frag

__device__ __forceinline__ float b2f(u16 u) { union { u32 i; float f; } v; v.i = (u32)u << 16; return v.f; }
__device__ __forceinline__ float lo2f(u32 u) { union { u32 i; float f; } v; v.i = u << 16; return v.f; }
__device__ __forceinline__ float hi2f(u32 u) { union { u32 i; float f; } v; v.i = u & 0xffff0000u; return v.f; }
__device__ __forceinline__ u16 f2b(float f) {
    union { float f; u32 i; } v; v.f = f;
    u32 r = v.i + 0x7fffu + ((v.i >> 16) & 1u);  // RTNE
    return (u16)(r >> 16);
}
__device__ __forceinline__ u32 pk2_rtz(float a, float b) {
    return (__float_as_uint(a) >> 16) | (__float_as_uint(b) & 0xffff0000u);
}
__device__ __forceinline__ void async_cp16(const u16* g, u16* l) {
    __builtin_amdgcn_global_load_lds((const __attribute__((address_space(1))) void*)g,
                                     (__attribute__((address_space(3))) void*)l, 16, 0, 0);
}

// ---------------- fused prep (wqkv pack + 3 transposes) + LN1 ---------------
__global__ __launch_bounds__(256) void prep_ln1(const float* __restrict__ wq,
                                                const float* __restrict__ wk,
                                                const float* __restrict__ wv,
                                                const float* __restrict__ wp,
                                                const float* __restrict__ w1,
                                                const float* __restrict__ w2,
                                                const float* __restrict__ x,
                                                const float* __restrict__ g1,
                                                const float* __restrict__ be1,
                                                u16* __restrict__ wqkvT,
                                                u16* __restrict__ wpT,
                                                u16* __restrict__ w1T,
                                                u16* __restrict__ w2T,
                                                u16* __restrict__ hout) {
    __shared__ u16 tile[64][65];
    int bid = blockIdx.x, tid = threadIdx.x;
    if (bid < 768) {
        int i = bid * 256 + tid;
        int n = i >> 8, k = i & 255;
        int which = n >> 8, nn = n & 255;
        const float* w = which == 0 ? wq : (which == 1 ? wk : wv);
        float v = w[((nn >> 5) * 256 + k) * 32 + (nn & 31)];   // w[h][k][d]
        if (which == 0) v *= 0.09016844f;                      // (1/16)*log2(e)
        wqkvT[i] = f2b(v);
    } else if (bid < 912) {
        const float* src; u16* dst; int K, N, t;
        if (bid < 784)      { src = wp; dst = wpT; K = 256;  N = 256;  t = bid - 768; }
        else if (bid < 848) { src = w1; dst = w1T; K = 256;  N = 1024; t = bid - 784; }
        else                { src = w2; dst = w2T; K = 1024; N = 256;  t = bid - 848; }
        int ntn = N >> 6;
        int k0 = (t / ntn) << 6, n0 = (t % ntn) << 6;
        int lane = tid & 63, wrow = tid >> 6;
        #pragma unroll
        for (int r = 0; r < 16; r++) {
            int k = wrow * 16 + r;
            tile[k][lane] = f2b(src[(size_t)(k0 + k) * N + n0 + lane]);
        }
        __syncthreads();
        #pragma unroll
        for (int r = 0; r < 16; r++) {
            int n = wrow * 16 + r;
            dst[(size_t)(n0 + n) * K + k0 + lane] = tile[lane][n];
        }
    } else {
        int row = (bid - 912) * 4 + (tid >> 6);
        int lane = tid & 63;
        float4 xv = *(const float4*)(x + (size_t)row * 256 + lane * 4);
        float v0 = xv.x, v1 = xv.y, v2 = xv.z, v3 = xv.w;
        float s = v0 + v1 + v2 + v3;
        #pragma unroll
        for (int m = 32; m; m >>= 1) s += __shfl_xor(s, m);
        float mu = s * 0.00390625f;
        float d0 = v0 - mu, d1 = v1 - mu, d2 = v2 - mu, d3 = v3 - mu;
        float ss = d0 * d0 + d1 * d1 + d2 * d2 + d3 * d3;
        #pragma unroll
        for (int m = 32; m; m >>= 1) ss += __shfl_xor(ss, m);
        float rs = rsqrtf(ss * 0.00390625f + 1e-5f);
        float4 g = *(const float4*)(g1 + lane * 4);
        float4 b = *(const float4*)(be1 + lane * 4);
        uint2 r;
        r.x = (u32)f2b(d0 * rs * g.x + b.x) | ((u32)f2b(d1 * rs * g.y + b.y) << 16);
        r.y = (u32)f2b(d2 * rs * g.z + b.z) | ((u32)f2b(d3 * rs * g.w + b.w) << 16);
        *(uint2*)(hout + (size_t)row * 256 + lane * 4) = r;
    }
}

// ---------------- 128x128 MFMA GEMM (qkv): counted-vmcnt double buffer ------
template<bool HASBIAS, bool RELU, bool QKV>
__global__ __launch_bounds__(256) void gemm128(const u16* __restrict__ A,
                                               const u16* __restrict__ Bt,
                                               const float* __restrict__ bias,
                                               u16* __restrict__ out,
                                               u16* __restrict__ vout,
                                               int M, int N, int K) {
    __shared__ __align__(16) u16 SH[32768];      // 64KB
    const int tid = threadIdx.x, lane = tid & 63, w = tid >> 6;
    const int m0 = blockIdx.x * 128, n0 = blockIdx.y * 128;
    const int wm = (w & 1) * 64, wn = (w >> 1) * 64;
    const int fm = lane & 15, q = lane >> 4;

    float4v acc[4][4];
    #pragma unroll
    for (int i = 0; i < 4; i++)
        #pragma unroll
        for (int j = 0; j < 4; j++) acc[i][j] = (float4v){0.f, 0.f, 0.f, 0.f};

    const int kset = ((lane & 7) ^ (lane >> 3)) * 8;
    const u16* Ag = A  + (size_t)(m0 + w * 32 + (lane >> 3)) * K + kset;
    const u16* Bg = Bt + (size_t)(n0 + w * 32 + (lane >> 3)) * K + kset;

    auto issueS = [&](int t, int d) {
        u16* Asw = SH + d * 16384 + (w * 32) * 64;
        u16* Bsw = SH + d * 16384 + 8192 + (w * 32) * 64;
        #pragma unroll
        for (int c = 0; c < 4; c++) {
            async_cp16(Ag + (size_t)c * 8 * K + t * 64, Asw + c * 8 * 64);
            async_cp16(Bg + (size_t)c * 8 * K + t * 64, Bsw + c * 8 * 64);
        }
    };
    issueS(0, 0);
    issueS(1, 1);

    const int sw = fm & 7;
    #pragma unroll
    for (int t = 0; t < 4; ++t) {
        if (t == 3) asm volatile("s_waitcnt vmcnt(0)" ::: "memory");
        else        asm volatile("s_waitcnt vmcnt(8)" ::: "memory");
        __builtin_amdgcn_s_barrier();
        const u16* As = SH + (t & 1) * 16384;
        const u16* Bs = As + 8192;
        #pragma unroll
        for (int kk = 0; kk < 64; kk += 32) {
            const int slot = (((kk >> 3) + q) ^ sw) * 8;
            short8v af[4], bf[4];
            #pragma unroll
            for (int mi = 0; mi < 4; mi++)
                af[mi] = *(const short8v*)&As[(wm + mi * 16 + fm) * 64 + slot];
            #pragma unroll
            for (int ni = 0; ni < 4; ni++)
                bf[ni] = *(const short8v*)&Bs[(wn + ni * 16 + fm) * 64 + slot];
            #pragma unroll
            for (int mi = 0; mi < 4; mi++)
                #pragma unroll
                for (int ni = 0; ni < 4; ni++)
                    acc[mi][ni] = __builtin_amdgcn_mfma_f32_16x16x32_bf16(
                        bf[ni], af[mi], acc[mi][ni], 0, 0, 0);
        }
        if (t < 2) {
            __builtin_amdgcn_s_barrier();
            issueS(t + 2, t & 1);
        }
    }

    if (QKV && n0 >= 512) {
        __syncthreads();
        #pragma unroll
        for (int mi = 0; mi < 4; mi++) {
            int ml = wm + mi * 16 + fm;
            #pragma unroll
            for (int ni = 0; ni < 4; ni++) {
                int nl = wn + ni * 16 + q * 4;
                #pragma unroll
                for (int r = 0; r < 4; r++)
                    SH[(nl + r) * 136 + ml] = f2b(acc[mi][ni][r]);
            }
        }
        __syncthreads();
        int r = tid & 127, c = (tid >> 7) << 6;
        int hd = (n0 - 512) + r;
        int b = m0 >> 10, t0 = m0 & 1023;
        u16* dst = vout + (size_t)(b * 256 + hd) * 1024 + t0 + c;
        const u16* srcT = SH + r * 136 + c;
        #pragma unroll
        for (int i = 0; i < 8; i++)
            *(uint4*)(dst + i * 8) = *(const uint4*)(srcT + i * 8);
        return;
    }

    #pragma unroll
    for (int mi = 0; mi < 4; mi++) {
        int row = m0 + wm + mi * 16 + fm;
        #pragma unroll
        for (int ni = 0; ni < 4; ni++) {
            int nb = n0 + wn + ni * 16 + q * 4;
            float v0 = acc[mi][ni][0], v1 = acc[mi][ni][1],
                  v2 = acc[mi][ni][2], v3 = acc[mi][ni][3];
            if (HASBIAS) {
                float4 bv = *(const float4*)&bias[nb];
                v0 += bv.x; v1 += bv.y; v2 += bv.z; v3 += bv.w;
            }
            if (RELU) {
                v0 = fmaxf(v0, 0.f); v1 = fmaxf(v1, 0.f);
                v2 = fmaxf(v2, 0.f); v3 = fmaxf(v3, 0.f);
            }
            size_t idx = (size_t)row * N + nb;
            uint2 ov;
            ov.x = (u32)f2b(v0) | ((u32)f2b(v1) << 16);
            ov.y = (u32)f2b(v2) | ((u32)f2b(v3) << 16);
            *(uint2*)&out[idx] = ov;
        }
    }
}

// ---------------- tail_fused: proj + LN2 + FFN, one kernel ------------------
// 64-row strips, 512 threads (8 waves = 2m x 4n), grid 256 = 1 block/CU.
// 36-tile counted-vmcnt B-stream: tiles 0-3 = wpT (proj), 4-35 = w1/w2 (ffn).
// After tile 3: LN2 interlude — x2 = acc + bp + x (fp32 regs), row stats via
// quad-shuffle + ps/pq LDS exchange, h2 -> Ms-region LDS (swizzled), reload
// into ar regs. Ms region reused for mid chunks from tile 11 on (ar dead).
// LDS 128KB: Ms/Hs 32K | Bs 3x32K (+2KB stats). vmcnt(0) only at tile 35.
__global__ __launch_bounds__(512, 1) void tail_fused(const u16* __restrict__ att,
                                                     const u16* __restrict__ wpT,
                                                     const float* __restrict__ bp,
                                                     const float* __restrict__ x,
                                                     const float* __restrict__ g2,
                                                     const float* __restrict__ be2,
                                                     const u16* __restrict__ w1T,
                                                     const float* __restrict__ b1,
                                                     const u16* __restrict__ w2T,
                                                     const float* __restrict__ b2,
                                                     float* __restrict__ out) {
    __shared__ __align__(16) u16 SH[65536];   // 128KB: Ms/Hs 32K | Bs 3x32K
    __shared__ float ps[2][2][16][4], pq[2][2][16][4];
    u16* Ms = SH;             // [4 kc][64][64]: h2 (interlude) then mid chunks
    u16* Bs = SH + 16384;     // 3 x [256][64] weight tile (triple buffer)
    const int tid = threadIdx.x, lane = tid & 63, w = tid >> 6;
    const int m0 = blockIdx.x * 64;
    const int wmi = w & 1, wni = w >> 1;
    const int wm = wmi * 32;                  // m-half (32 rows)
    const int wn = wni * 64;                  // n-quarter (64 cols)
    const int fm = lane & 15, q = lane >> 4;
    const int sw = fm & 7;
    const int kset = ((lane & 7) ^ (lane >> 3)) * 8;
    const int rb = w * 8 + (lane >> 3);       // staging row 0..63

    // ---- A-frags (att) into registers: ar[kcn][mi] = att[row][kcn*32+q*8] --
    short8v ar[8][2];
    {
        const u16* Abase = att + (size_t)(m0 + wm + fm) * 256 + q * 8;
        #pragma unroll
        for (int kcn = 0; kcn < 8; kcn++)
            #pragma unroll
            for (int mi = 0; mi < 2; mi++)
                ar[kcn][mi] = *(const short8v*)(Abase + (size_t)mi * 16 * 256 + kcn * 32);
    }

    // ---- B-tile issue: u<4 -> wpT chunk u; u>=4 -> ffn tile u-4 ----
    auto issueB = [&](int u, u16* dst) {
        if (u < 4) {
            const u16* src = wpT + (size_t)rb * 256 + u * 64 + kset;
            #pragma unroll
            for (int c = 0; c < 4; c++)
                async_cp16(src + (size_t)c * 64 * 256, dst + c * 4096);
        } else {
            const int tt = u - 4, n2 = tt >> 3, k2 = tt & 3;
            if (((tt >> 2) & 1) == 0) {
                const u16* src = w1T + (size_t)(n2 * 256 + rb) * 256 + k2 * 64 + kset;
                #pragma unroll
                for (int c = 0; c < 4; c++)
                    async_cp16(src + (size_t)c * 64 * 256, dst + c * 4096);
            } else {
                const u16* src = w2T + (size_t)rb * 1024 + n2 * 256 + k2 * 64 + kset;
                #pragma unroll
                for (int c = 0; c < 4; c++)
                    async_cp16(src + (size_t)c * 64 * 1024, dst + c * 4096);
            }
        }
    };

    issueB(0, Bs + w * 512);
    issueB(1, Bs + 16384 + w * 512);

    float4v acc1[2][4], acc2[2][4], xr[2][4];
    #pragma unroll
    for (int i = 0; i < 2; i++)
        #pragma unroll
        for (int j = 0; j < 4; j++) {
            acc1[i][j] = (float4v){0.f, 0.f, 0.f, 0.f};   // proj accumulator
            acc2[i][j] = (float4v){0.f, 0.f, 0.f, 0.f};
        }

    #pragma unroll
    for (int t = 0; t < 36; ++t) {
        if (t == 35) asm volatile("s_waitcnt vmcnt(0)" ::: "memory");
        else         asm volatile("s_waitcnt vmcnt(4)" ::: "memory");
        __builtin_amdgcn_s_barrier();
        if (t + 2 < 36)
            issueB(t + 2, Bs + ((t + 2) % 3) * 16384 + w * 512);
        const u16* Bb = Bs + (t % 3) * 16384;

        if (t < 4) {
            // ---- proj tile t: acc1 += att-frag x wpT-tile ----
            #pragma unroll
            for (int kk = 0; kk < 64; kk += 32) {
                const int slot = (((kk >> 3) + q) ^ sw) * 8;
                short8v bf[4];
                #pragma unroll
                for (int ni = 0; ni < 4; ni++)
                    bf[ni] = *(const short8v*)&Bb[(wn + ni * 16 + fm) * 64 + slot];
                #pragma unroll
                for (int mi = 0; mi < 2; mi++)
                    #pragma unroll
                    for (int ni = 0; ni < 4; ni++)
                        acc1[mi][ni] = __builtin_amdgcn_mfma_f32_16x16x32_bf16(
                            bf[ni], ar[t * 2 + (kk >> 5)][mi], acc1[mi][ni], 0, 0, 0);
            }
            if (t == 3) {
                // ======== LN2 interlude ========
                float s[2] = {0.f, 0.f}, s2[2] = {0.f, 0.f};
                #pragma unroll
                for (int mi = 0; mi < 2; mi++)
                    #pragma unroll
                    for (int ni = 0; ni < 4; ni++) {
                        const int nb = wn + ni * 16 + q * 4;
                        const int row = m0 + wm + mi * 16 + fm;
                        float4 bv = *(const float4*)&bp[nb];
                        float4 xv = *(const float4*)(x + (size_t)row * 256 + nb);
                        #pragma unroll
                        for (int r = 0; r < 4; r++) {
                            float tv = acc1[mi][ni][r] + (&bv.x)[r] + (&xv.x)[r];
                            xr[mi][ni][r] = tv;
                            s[mi] += tv; s2[mi] += tv * tv;
                        }
                    }
                #pragma unroll
                for (int mi = 0; mi < 2; mi++) {
                    s[mi]  += __shfl_xor(s[mi], 16);  s[mi]  += __shfl_xor(s[mi], 32);
                    s2[mi] += __shfl_xor(s2[mi], 16); s2[mi] += __shfl_xor(s2[mi], 32);
                }
                if (q == 0) {
                    ps[wmi][0][fm][wni] = s[0];  ps[wmi][1][fm][wni] = s[1];
                    pq[wmi][0][fm][wni] = s2[0]; pq[wmi][1][fm][wni] = s2[1];
                }
                asm volatile("s_waitcnt lgkmcnt(0)" ::: "memory");
                __builtin_amdgcn_s_barrier();
                float mu[2], rs[2];
                #pragma unroll
                for (int mi = 0; mi < 2; mi++) {
                    float S  = ps[wmi][mi][fm][0] + ps[wmi][mi][fm][1]
                             + ps[wmi][mi][fm][2] + ps[wmi][mi][fm][3];
                    float SQ = pq[wmi][mi][fm][0] + pq[wmi][mi][fm][1]
                             + pq[wmi][mi][fm][2] + pq[wmi][mi][fm][3];
                    mu[mi] = S * 0.00390625f;
                    rs[mi] = rsqrtf(SQ * 0.00390625f - mu[mi] * mu[mi] + 1e-5f);
                }
                // h2 -> Ms (Hs) in swizzled A layout
                #pragma unroll
                for (int ni = 0; ni < 4; ni++) {
                    const int c2 = wn + ni * 16 + q * 4;
                    const int kcM = c2 >> 6, cc = c2 & 63;
                    float4 gv = *(const float4*)&g2[c2];
                    float4 bv = *(const float4*)&be2[c2];
                    #pragma unroll
                    for (int mi = 0; mi < 2; mi++) {
                        const int row = wm + mi * 16 + fm;
                        float h0 = (xr[mi][ni][0] - mu[mi]) * rs[mi] * gv.x + bv.x;
                        float h1 = (xr[mi][ni][1] - mu[mi]) * rs[mi] * gv.y + bv.y;
                        float h2v = (xr[mi][ni][2] - mu[mi]) * rs[mi] * gv.z + bv.z;
                        float h3 = (xr[mi][ni][3] - mu[mi]) * rs[mi] * gv.w + bv.w;
                        uint2 pp;
                        pp.x = (u32)f2b(h0) | ((u32)f2b(h1) << 16);
                        pp.y = (u32)f2b(h2v) | ((u32)f2b(h3) << 16);
                        *(uint2*)&Ms[kcM * 4096 + row * 64 +
                                     (((cc >> 3) ^ (row & 7)) * 8) + (cc & 7)] = pp;
                    }
                }
                asm volatile("s_waitcnt lgkmcnt(0)" ::: "memory");
                __builtin_amdgcn_s_barrier();
                // reload ar from Ms(Hs): ar[kcn][mi] = h2[row][kcn*32 + q*8]
                #pragma unroll
                for (int kcn = 0; kcn < 8; kcn++) {
                    const int kcq = kcn >> 1, kk = (kcn & 1) * 32;
                    const int slot = (((kk >> 3) + q) ^ sw) * 8;
                    #pragma unroll
                    for (int mi = 0; mi < 2; mi++)
                        ar[kcn][mi] = *(const short8v*)&Ms[kcq * 4096 +
                                        (wm + mi * 16 + fm) * 64 + slot];
                }
            }
        } else {
            const int tt = t - 4;
            const int nch = tt >> 3, ph = (tt >> 2) & 1, kc = tt & 3;
            if (ph == 0) {
                if (kc == 0) {
                    #pragma unroll
                    for (int i = 0; i < 2; i++)
                        #pragma unroll
                        for (int j = 0; j < 4; j++) acc1[i][j] = (float4v){0.f, 0.f, 0.f, 0.f};
                }
                #pragma unroll
                for (int kk = 0; kk < 64; kk += 32) {
                    const int slot = (((kk >> 3) + q) ^ sw) * 8;
                    short8v bf[4];
                    #pragma unroll
                    for (int ni = 0; ni < 4; ni++)
                        bf[ni] = *(const short8v*)&Bb[(wn + ni * 16 + fm) * 64 + slot];
                    #pragma unroll
                    for (int mi = 0; mi < 2; mi++)
                        #pragma unroll
                        for (int ni = 0; ni < 4; ni++)
                            acc1[mi][ni] = __builtin_amdgcn_mfma_f32_16x16x32_bf16(
                                bf[ni], ar[kc * 2 + (kk >> 5)][mi], acc1[mi][ni], 0, 0, 0);
                }
                if (kc == 3) {
                    // bias + relu -> Ms (swizzled A layout for gemm2)
                    #pragma unroll
                    for (int ni = 0; ni < 4; ni++) {
                        const int c2 = wn + ni * 16 + q * 4;       // 0..255
                        const int kcM = c2 >> 6, cc = c2 & 63;
                        float4 bv = *(const float4*)&b1[nch * 256 + c2];
                        #pragma unroll
                        for (int mi = 0; mi < 2; mi++) {
                            const int row = wm + mi * 16 + fm;
                            float v0 = fmaxf(acc1[mi][ni][0] + bv.x, 0.f);
                            float v1 = fmaxf(acc1[mi][ni][1] + bv.y, 0.f);
                            float v2 = fmaxf(acc1[mi][ni][2] + bv.z, 0.f);
                            float v3 = fmaxf(acc1[mi][ni][3] + bv.w, 0.f);
                            uint2 pp;
                            pp.x = (u32)f2b(v0) | ((u32)f2b(v1) << 16);
                            pp.y = (u32)f2b(v2) | ((u32)f2b(v3) << 16);
                            *(uint2*)&Ms[kcM * 4096 + row * 64 +
                                         (((cc >> 3) ^ (row & 7)) * 8) + (cc & 7)] = pp;
                        }
                    }
                    asm volatile("s_waitcnt lgkmcnt(0)" ::: "memory");
                }
            } else {
                const u16* Ab = Ms + kc * 4096;
                #pragma unroll
                for (int kk = 0; kk < 64; kk += 32) {
                    const int slot = (((kk >> 3) + q) ^ sw) * 8;
                    short8v af[2], bf[4];
                    #pragma unroll
                    for (int mi = 0; mi < 2; mi++)
                        af[mi] = *(const short8v*)&Ab[(wm + mi * 16 + fm) * 64 + slot];
                    #pragma unroll
                    for (int ni = 0; ni < 4; ni++)
                        bf[ni] = *(const short8v*)&Bb[(wn + ni * 16 + fm) * 64 + slot];
                    #pragma unroll
                    for (int mi = 0; mi < 2; mi++)
                        #pragma unroll
                        for (int ni = 0; ni < 4; ni++)
                            acc2[mi][ni] = __builtin_amdgcn_mfma_f32_16x16x32_bf16(
                                bf[ni], af[mi], acc2[mi][ni], 0, 0, 0);
                }
            }
        }
    }

    // ---- epilogue: out = xr (= x + att@wp + bp) + acc2 + b2, fp32 stores ---
    #pragma unroll
    for (int mi = 0; mi < 2; mi++) {
        const int row = m0 + wm + mi * 16 + fm;
        #pragma unroll
        for (int ni = 0; ni < 4; ni++) {
            const int nb = wn + ni * 16 + q * 4;
            size_t idx = (size_t)row * 256 + nb;
            float4 bv = *(const float4*)&b2[nb];
            float v0 = acc2[mi][ni][0] + bv.x + xr[mi][ni][0];
            float v1 = acc2[mi][ni][1] + bv.y + xr[mi][ni][1];
            float v2 = acc2[mi][ni][2] + bv.z + xr[mi][ni][2];
            float v3 = acc2[mi][ni][3] + bv.w + xr[mi][ni][3];
            *(float4*)&out[idx] = (float4){v0, v1, v2, v3};
        }
    }
}

// ---------------- MFMA flash attention: single sweep, dual q-tile -----------
__global__ __launch_bounds__(256) void attn_mfma(const u16* __restrict__ qk,
                                                 const u16* __restrict__ vtg,
                                                 u16* __restrict__ att) {
    const int T = 1024;
    int jj = (blockIdx.x + (blockIdx.y >> 3)) & 7;
    int b = blockIdx.y >> 3, hh = blockIdx.y & 7;
    int tid = threadIdx.x;
    int lane = tid & 63, w = tid >> 6;
    int fm = lane & 15, q = lane >> 4;

    __shared__ __align__(16) u16 Ks[64][72];
    __shared__ __align__(16) u16 Vt[32][72];
    __shared__ __align__(16) u16 Pl[4][16][72];

    size_t base = (size_t)b * T * 512;
    const u16* kb = qk + base + 256 + hh * 32;
    const u16* vt = vtg + (size_t)((b * 8 + hh) * 32) * 1024;
    const int krow = tid >> 2, kcol = (tid & 3) * 8;
    const int vd = tid >> 3, vs = (tid & 7) * 8;

    int qa0 = jj * 64, qb0 = (15 - jj) * 64;
    int tqa = qa0 + w * 16 + fm, tqb = qb0 + w * 16 + fm;
    short8v qfa = *(const short8v*)(qk + base + (size_t)tqa * 512 + hh * 32 + q * 8);
    short8v qfb = *(const short8v*)(qk + base + (size_t)tqb * 512 + hh * 32 + q * 8);
    float4v oa0 = {0.f, 0.f, 0.f, 0.f}, oa1 = {0.f, 0.f, 0.f, 0.f};
    float4v ob0 = {0.f, 0.f, 0.f, 0.f}, ob1 = {0.f, 0.f, 0.f, 0.f};
    float la = 0.f, lb = 0.f;
    int wqa = qa0 + w * 16, wqb = qb0 + w * 16;
    int nIter = 16 - jj;

    uint4 kreg = *(const uint4*)(kb + (size_t)krow * 512 + kcol);
    uint4 vreg = *(const uint4*)(vt + (size_t)vd * 1024 + vs);

    for (int it = 0; it < nIter; ++it) {
        int s0 = it << 6;
        __syncthreads();
        *(uint4*)&Ks[krow][kcol] = kreg;
        *(uint4*)&Vt[vd][vs] = vreg;
        __syncthreads();
        if (it + 1 < nIter) {
            int ns0 = s0 + 64;
            kreg = *(const uint4*)(kb + (size_t)(ns0 + krow) * 512 + kcol);
            vreg = *(const uint4*)(vt + (size_t)vd * 1024 + ns0 + vs);
        }
        short8v kf0 = *(const short8v*)&Ks[fm][q * 8];
        short8v kf1 = *(const short8v*)&Ks[16 + fm][q * 8];
        short8v kf2 = *(const short8v*)&Ks[32 + fm][q * 8];
        short8v kf3 = *(const short8v*)&Ks[48 + fm][q * 8];
        short8v vf00 = *(const short8v*)&Vt[fm][q * 8];
        short8v vf01 = *(const short8v*)&Vt[fm][32 + q * 8];
        short8v vf10 = *(const short8v*)&Vt[16 + fm][q * 8];
        short8v vf11 = *(const short8v*)&Vt[16 + fm][32 + q * 8];
        float4v z = {0.f, 0.f, 0.f, 0.f};

        #pragma unroll
        for (int t2 = 0; t2 < 2; t2++) {       // t2=0: tile b (large), 1: tile a
            int wq0 = t2 ? wqa : wqb;
            if (s0 >= wq0 + 16) continue;      // wave-uniform causal skip
            int tq = t2 ? tqa : tqb;
            short8v qf = t2 ? qfa : qfb;
            float4v s_0 = __builtin_amdgcn_mfma_f32_16x16x32_bf16(kf0, qf, z, 0, 0, 0);
            float4v s_1 = __builtin_amdgcn_mfma_f32_16x16x32_bf16(kf1, qf, z, 0, 0, 0);
            float4v s_2 = __builtin_amdgcn_mfma_f32_16x16x32_bf16(kf2, qf, z, 0, 0, 0);
            float4v s_3 = __builtin_amdgcn_mfma_f32_16x16x32_bf16(kf3, qf, z, 0, 0, 0);
            float p[16];
            #pragma unroll
            for (int r = 0; r < 4; r++) {
                p[r] = exp2f(s_0[r]); p[4 + r] = exp2f(s_1[r]);
                p[8 + r] = exp2f(s_2[r]); p[12 + r] = exp2f(s_3[r]);
            }
            if (s0 + 63 > wq0) {               // diagonal region: causal mask
                int sb = s0 + q * 4;
                #pragma unroll
                for (int c = 0; c < 4; c++)
                    #pragma unroll
                    for (int r = 0; r < 4; r++)
                        if (sb + c * 16 + r > tq) p[c * 4 + r] = 0.f;
            }
            float rsum = 0.f;
            #pragma unroll
            for (int i = 0; i < 16; i++) rsum += p[i];
            rsum += __shfl_xor(rsum, 16);
            rsum += __shfl_xor(rsum, 32);
            if (t2) la += rsum; else lb += rsum;

            #pragma unroll
            for (int c = 0; c < 4; c++) {
                uint2 pp;
                pp.x = pk2_rtz(p[c * 4 + 0], p[c * 4 + 1]);
                pp.y = pk2_rtz(p[c * 4 + 2], p[c * 4 + 3]);
                *(uint2*)&Pl[w][fm][c * 16 + q * 4] = pp;   // wave-internal
            }
            short8v pf0 = *(const short8v*)&Pl[w][fm][q * 8];
            short8v pf1 = *(const short8v*)&Pl[w][fm][32 + q * 8];
            if (t2) {
                oa0 = __builtin_amdgcn_mfma_f32_16x16x32_bf16(vf00, pf0, oa0, 0, 0, 0);
                oa0 = __builtin_amdgcn_mfma_f32_16x16x32_bf16(vf01, pf1, oa0, 0, 0, 0);
                oa1 = __builtin_amdgcn_mfma_f32_16x16x32_bf16(vf10, pf0, oa1, 0, 0, 0);
                oa1 = __builtin_amdgcn_mfma_f32_16x16x32_bf16(vf11, pf1, oa1, 0, 0, 0);
            } else {
                ob0 = __builtin_amdgcn_mfma_f32_16x16x32_bf16(vf00, pf0, ob0, 0, 0, 0);
                ob0 = __builtin_amdgcn_mfma_f32_16x16x32_bf16(vf01, pf1, ob0, 0, 0, 0);
                ob1 = __builtin_amdgcn_mfma_f32_16x16x32_bf16(vf10, pf0, ob1, 0, 0, 0);
                ob1 = __builtin_amdgcn_mfma_f32_16x16x32_bf16(vf11, pf1, ob1, 0, 0, 0);
            }
        }
    }

    #pragma unroll
    for (int t2 = 0; t2 < 2; t2++) {
        float inv = 1.f / (t2 ? la : lb);
        float4v o0 = t2 ? oa0 : ob0, o1 = t2 ? oa1 : ob1;
        int tq = t2 ? tqa : tqb;
        uint2 r0, r1;
        r0.x = (u32)f2b(o0[0] * inv) | ((u32)f2b(o0[1] * inv) << 16);
        r0.y = (u32)f2b(o0[2] * inv) | ((u32)f2b(o0[3] * inv) << 16);
        r1.x = (u32)f2b(o1[0] * inv) | ((u32)f2b(o1[1] * inv) << 16);
        r1.y = (u32)f2b(o1[2] * inv) | ((u32)f2b(o1[3] * inv) << 16);
        size_t o = (size_t)(b * T + tq) * 256 + hh * 32;
        *(uint2*)(att + o + q * 4) = r0;
        *(uint2*)(att + o + 16 + q * 4) = r1;
    }
}

// ---------------- launch ----------------
extern "C" void kernel_launch(void* const* d_in, const int* in_sizes, int n_in,
                              void* d_out, int out_size, void* d_ws, size_t ws_size,
                              hipStream_t stream) {
    const int BT = 16 * 1024;
    const float* x      = (const float*)d_in[0];
    const float* wq     = (const float*)d_in[1];
    const float* wk     = (const float*)d_in[2];
    const float* wv     = (const float*)d_in[3];
    const float* w_proj = (const float*)d_in[4];
    const float* b_proj = (const float*)d_in[5];
    const float* w1     = (const float*)d_in[6];
    const float* b1     = (const float*)d_in[7];
    const float* w2     = (const float*)d_in[8];
    const float* b2     = (const float*)d_in[9];
    const float* ln1_g  = (const float*)d_in[10];
    const float* ln1_b  = (const float*)d_in[11];
    const float* ln2_g  = (const float*)d_in[12];
    const float* ln2_b  = (const float*)d_in[13];

    // Workspace (~49.5 MiB):
    //   [8M,16M)  hbuf: h -> att  [attn writes over h; tail reads att]
    //   [16M,32M) qk [BT,512] | [32M,48M) vtg  -> dead after attn
    //   [48M...)  packed weights (1.5M)
    char* ws = (char*)d_ws;
    const size_t MB = 1024 * 1024;
    u16*  hbuf  = (u16*)(ws + 8 * MB);
    u16*  qk    = (u16*)(ws + 16 * MB);
    u16*  vtg   = (u16*)(ws + 32 * MB);
    u16*  wqkvT = (u16*)(ws + 48 * MB);
    u16*  wpT   = (u16*)(ws + 48 * MB + 0x60000);
    u16*  w1T   = (u16*)(ws + 48 * MB + 0x80000);
    u16*  w2T   = (u16*)(ws + 48 * MB + 0x100000);

    prep_ln1<<<5008, 256, 0, stream>>>(wq, wk, wv, w_proj, w1, w2, x, ln1_g, ln1_b,
                                       wqkvT, wpT, w1T, w2T, hbuf);
    // qk | vtg = h @ [Wq'|Wk|Wv]  [counted-vmcnt dbuf]
    gemm128<false, false, true><<<dim3(128, 6), 256, 0, stream>>>(
        hbuf, wqkvT, nullptr, qk, vtg, BT, 512, 256);
    // att = flash attention (writes over h)
    attn_mfma<<<dim3(8, 128), 256, 0, stream>>>(qk, vtg, hbuf);
    // out = x2 + relu(LN2(x + att@wp + bp) @ w1 + b1) @ w2 + b2  [one kernel]
    tail_fused<<<256, 512, 0, stream>>>(hbuf, wpT, b_proj, x, ln2_g, ln2_b,
                                        w1T, b1, w2T, b2, (float*)d_out);
}

// Round 7
// 174.747 us; speedup vs baseline: 1.0796x; 1.0115x over previous
//
#include <hip/hip_runtime.h>

// EncoderBlock on MI355X. Round 21: attn gets double-buffered Ks/Vt (ONE
// barrier per K/V tile instead of two) + s_setprio(1) around MFMA clusters
// in attn / tail_fused / gemm128 (T5). Math identical everywhere.
// r20 = 176.8 µs. B=16 T=1024 C=256 H=8 D=32. 4 launches.

typedef unsigned short u16;
typedef unsigned int u32;
typedef __attribute__((ext_vector_type(8))) short short8v;  // 8 bf16 MFMA A/B frag
typedef __attribute__((ext_vector_type(4))) float float4v;  // MFMA C/D frag

__device__ __forceinline__ float b2f(u16 u) { union { u32 i; float f; } v; v.i = (u32)u << 16; return v.f; }
__device__ __forceinline__ float lo2f(u32 u) { union { u32 i; float f; } v; v.i = u << 16; return v.f; }
__device__ __forceinline__ float hi2f(u32 u) { union { u32 i; float f; } v; v.i = u & 0xffff0000u; return v.f; }
__device__ __forceinline__ u16 f2b(float f) {
    union { float f; u32 i; } v; v.f = f;
    u32 r = v.i + 0x7fffu + ((v.i >> 16) & 1u);  // RTNE
    return (u16)(r >> 16);
}
__device__ __forceinline__ u32 pk2_rtz(float a, float b) {
    return (__float_as_uint(a) >> 16) | (__float_as_uint(b) & 0xffff0000u);
}
__device__ __forceinline__ void async_cp16(const u16* g, u16* l) {
    __builtin_amdgcn_global_load_lds((const __attribute__((address_space(1))) void*)g,
                                     (__attribute__((address_space(3))) void*)l, 16, 0, 0);
}

// ---------------- fused prep (wqkv pack + 3 transposes) + LN1 ---------------
__global__ __launch_bounds__(256) void prep_ln1(const float* __restrict__ wq,
                                                const float* __restrict__ wk,
                                                const float* __restrict__ wv,
                                                const float* __restrict__ wp,
                                                const float* __restrict__ w1,
                                                const float* __restrict__ w2,
                                                const float* __restrict__ x,
                                                const float* __restrict__ g1,
                                                const float* __restrict__ be1,
                                                u16* __restrict__ wqkvT,
                                                u16* __restrict__ wpT,
                                                u16* __restrict__ w1T,
                                                u16* __restrict__ w2T,
                                                u16* __restrict__ hout) {
    __shared__ u16 tile[64][65];
    int bid = blockIdx.x, tid = threadIdx.x;
    if (bid < 768) {
        int i = bid * 256 + tid;
        int n = i >> 8, k = i & 255;
        int which = n >> 8, nn = n & 255;
        const float* w = which == 0 ? wq : (which == 1 ? wk : wv);
        float v = w[((nn >> 5) * 256 + k) * 32 + (nn & 31)];   // w[h][k][d]
        if (which == 0) v *= 0.09016844f;                      // (1/16)*log2(e)
        wqkvT[i] = f2b(v);
    } else if (bid < 912) {
        const float* src; u16* dst; int K, N, t;
        if (bid < 784)      { src = wp; dst = wpT; K = 256;  N = 256;  t = bid - 768; }
        else if (bid < 848) { src = w1; dst = w1T; K = 256;  N = 1024; t = bid - 784; }
        else                { src = w2; dst = w2T; K = 1024; N = 256;  t = bid - 848; }
        int ntn = N >> 6;
        int k0 = (t / ntn) << 6, n0 = (t % ntn) << 6;
        int lane = tid & 63, wrow = tid >> 6;
        #pragma unroll
        for (int r = 0; r < 16; r++) {
            int k = wrow * 16 + r;
            tile[k][lane] = f2b(src[(size_t)(k0 + k) * N + n0 + lane]);
        }
        __syncthreads();
        #pragma unroll
        for (int r = 0; r < 16; r++) {
            int n = wrow * 16 + r;
            dst[(size_t)(n0 + n) * K + k0 + lane] = tile[lane][n];
        }
    } else {
        int row = (bid - 912) * 4 + (tid >> 6);
        int lane = tid & 63;
        float4 xv = *(const float4*)(x + (size_t)row * 256 + lane * 4);
        float v0 = xv.x, v1 = xv.y, v2 = xv.z, v3 = xv.w;
        float s = v0 + v1 + v2 + v3;
        #pragma unroll
        for (int m = 32; m; m >>= 1) s += __shfl_xor(s, m);
        float mu = s * 0.00390625f;
        float d0 = v0 - mu, d1 = v1 - mu, d2 = v2 - mu, d3 = v3 - mu;
        float ss = d0 * d0 + d1 * d1 + d2 * d2 + d3 * d3;
        #pragma unroll
        for (int m = 32; m; m >>= 1) ss += __shfl_xor(ss, m);
        float rs = rsqrtf(ss * 0.00390625f + 1e-5f);
        float4 g = *(const float4*)(g1 + lane * 4);
        float4 b = *(const float4*)(be1 + lane * 4);
        uint2 r;
        r.x = (u32)f2b(d0 * rs * g.x + b.x) | ((u32)f2b(d1 * rs * g.y + b.y) << 16);
        r.y = (u32)f2b(d2 * rs * g.z + b.z) | ((u32)f2b(d3 * rs * g.w + b.w) << 16);
        *(uint2*)(hout + (size_t)row * 256 + lane * 4) = r;
    }
}

// ---------------- 128x128 MFMA GEMM (qkv): counted-vmcnt double buffer ------
template<bool HASBIAS, bool RELU, bool QKV>
__global__ __launch_bounds__(256) void gemm128(const u16* __restrict__ A,
                                               const u16* __restrict__ Bt,
                                               const float* __restrict__ bias,
                                               u16* __restrict__ out,
                                               u16* __restrict__ vout,
                                               int M, int N, int K) {
    __shared__ __align__(16) u16 SH[32768];      // 64KB
    const int tid = threadIdx.x, lane = tid & 63, w = tid >> 6;
    const int m0 = blockIdx.x * 128, n0 = blockIdx.y * 128;
    const int wm = (w & 1) * 64, wn = (w >> 1) * 64;
    const int fm = lane & 15, q = lane >> 4;

    float4v acc[4][4];
    #pragma unroll
    for (int i = 0; i < 4; i++)
        #pragma unroll
        for (int j = 0; j < 4; j++) acc[i][j] = (float4v){0.f, 0.f, 0.f, 0.f};

    const int kset = ((lane & 7) ^ (lane >> 3)) * 8;
    const u16* Ag = A  + (size_t)(m0 + w * 32 + (lane >> 3)) * K + kset;
    const u16* Bg = Bt + (size_t)(n0 + w * 32 + (lane >> 3)) * K + kset;

    auto issueS = [&](int t, int d) {
        u16* Asw = SH + d * 16384 + (w * 32) * 64;
        u16* Bsw = SH + d * 16384 + 8192 + (w * 32) * 64;
        #pragma unroll
        for (int c = 0; c < 4; c++) {
            async_cp16(Ag + (size_t)c * 8 * K + t * 64, Asw + c * 8 * 64);
            async_cp16(Bg + (size_t)c * 8 * K + t * 64, Bsw + c * 8 * 64);
        }
    };
    issueS(0, 0);
    issueS(1, 1);

    const int sw = fm & 7;
    #pragma unroll
    for (int t = 0; t < 4; ++t) {
        if (t == 3) asm volatile("s_waitcnt vmcnt(0)" ::: "memory");
        else        asm volatile("s_waitcnt vmcnt(8)" ::: "memory");
        __builtin_amdgcn_s_barrier();
        const u16* As = SH + (t & 1) * 16384;
        const u16* Bs = As + 8192;
        __builtin_amdgcn_s_setprio(1);
        #pragma unroll
        for (int kk = 0; kk < 64; kk += 32) {
            const int slot = (((kk >> 3) + q) ^ sw) * 8;
            short8v af[4], bf[4];
            #pragma unroll
            for (int mi = 0; mi < 4; mi++)
                af[mi] = *(const short8v*)&As[(wm + mi * 16 + fm) * 64 + slot];
            #pragma unroll
            for (int ni = 0; ni < 4; ni++)
                bf[ni] = *(const short8v*)&Bs[(wn + ni * 16 + fm) * 64 + slot];
            #pragma unroll
            for (int mi = 0; mi < 4; mi++)
                #pragma unroll
                for (int ni = 0; ni < 4; ni++)
                    acc[mi][ni] = __builtin_amdgcn_mfma_f32_16x16x32_bf16(
                        bf[ni], af[mi], acc[mi][ni], 0, 0, 0);
        }
        __builtin_amdgcn_s_setprio(0);
        if (t < 2) {
            __builtin_amdgcn_s_barrier();
            issueS(t + 2, t & 1);
        }
    }

    if (QKV && n0 >= 512) {
        __syncthreads();
        #pragma unroll
        for (int mi = 0; mi < 4; mi++) {
            int ml = wm + mi * 16 + fm;
            #pragma unroll
            for (int ni = 0; ni < 4; ni++) {
                int nl = wn + ni * 16 + q * 4;
                #pragma unroll
                for (int r = 0; r < 4; r++)
                    SH[(nl + r) * 136 + ml] = f2b(acc[mi][ni][r]);
            }
        }
        __syncthreads();
        int r = tid & 127, c = (tid >> 7) << 6;
        int hd = (n0 - 512) + r;
        int b = m0 >> 10, t0 = m0 & 1023;
        u16* dst = vout + (size_t)(b * 256 + hd) * 1024 + t0 + c;
        const u16* srcT = SH + r * 136 + c;
        #pragma unroll
        for (int i = 0; i < 8; i++)
            *(uint4*)(dst + i * 8) = *(const uint4*)(srcT + i * 8);
        return;
    }

    #pragma unroll
    for (int mi = 0; mi < 4; mi++) {
        int row = m0 + wm + mi * 16 + fm;
        #pragma unroll
        for (int ni = 0; ni < 4; ni++) {
            int nb = n0 + wn + ni * 16 + q * 4;
            float v0 = acc[mi][ni][0], v1 = acc[mi][ni][1],
                  v2 = acc[mi][ni][2], v3 = acc[mi][ni][3];
            if (HASBIAS) {
                float4 bv = *(const float4*)&bias[nb];
                v0 += bv.x; v1 += bv.y; v2 += bv.z; v3 += bv.w;
            }
            if (RELU) {
                v0 = fmaxf(v0, 0.f); v1 = fmaxf(v1, 0.f);
                v2 = fmaxf(v2, 0.f); v3 = fmaxf(v3, 0.f);
            }
            size_t idx = (size_t)row * N + nb;
            uint2 ov;
            ov.x = (u32)f2b(v0) | ((u32)f2b(v1) << 16);
            ov.y = (u32)f2b(v2) | ((u32)f2b(v3) << 16);
            *(uint2*)&out[idx] = ov;
        }
    }
}

// ---------------- tail_fused: proj + LN2 + FFN, one kernel ------------------
__global__ __launch_bounds__(512, 1) void tail_fused(const u16* __restrict__ att,
                                                     const u16* __restrict__ wpT,
                                                     const float* __restrict__ bp,
                                                     const float* __restrict__ x,
                                                     const float* __restrict__ g2,
                                                     const float* __restrict__ be2,
                                                     const u16* __restrict__ w1T,
                                                     const float* __restrict__ b1,
                                                     const u16* __restrict__ w2T,
                                                     const float* __restrict__ b2,
                                                     float* __restrict__ out) {
    __shared__ __align__(16) u16 SH[65536];   // 128KB: Ms/Hs 32K | Bs 3x32K
    __shared__ float ps[2][2][16][4], pq[2][2][16][4];
    u16* Ms = SH;             // [4 kc][64][64]: h2 (interlude) then mid chunks
    u16* Bs = SH + 16384;     // 3 x [256][64] weight tile (triple buffer)
    const int tid = threadIdx.x, lane = tid & 63, w = tid >> 6;
    const int m0 = blockIdx.x * 64;
    const int wmi = w & 1, wni = w >> 1;
    const int wm = wmi * 32;                  // m-half (32 rows)
    const int wn = wni * 64;                  // n-quarter (64 cols)
    const int fm = lane & 15, q = lane >> 4;
    const int sw = fm & 7;
    const int kset = ((lane & 7) ^ (lane >> 3)) * 8;
    const int rb = w * 8 + (lane >> 3);       // staging row 0..63

    // ---- A-frags (att) into registers: ar[kcn][mi] = att[row][kcn*32+q*8] --
    short8v ar[8][2];
    {
        const u16* Abase = att + (size_t)(m0 + wm + fm) * 256 + q * 8;
        #pragma unroll
        for (int kcn = 0; kcn < 8; kcn++)
            #pragma unroll
            for (int mi = 0; mi < 2; mi++)
                ar[kcn][mi] = *(const short8v*)(Abase + (size_t)mi * 16 * 256 + kcn * 32);
    }

    // ---- B-tile issue: u<4 -> wpT chunk u; u>=4 -> ffn tile u-4 ----
    auto issueB = [&](int u, u16* dst) {
        if (u < 4) {
            const u16* src = wpT + (size_t)rb * 256 + u * 64 + kset;
            #pragma unroll
            for (int c = 0; c < 4; c++)
                async_cp16(src + (size_t)c * 64 * 256, dst + c * 4096);
        } else {
            const int tt = u - 4, n2 = tt >> 3, k2 = tt & 3;
            if (((tt >> 2) & 1) == 0) {
                const u16* src = w1T + (size_t)(n2 * 256 + rb) * 256 + k2 * 64 + kset;
                #pragma unroll
                for (int c = 0; c < 4; c++)
                    async_cp16(src + (size_t)c * 64 * 256, dst + c * 4096);
            } else {
                const u16* src = w2T + (size_t)rb * 1024 + n2 * 256 + k2 * 64 + kset;
                #pragma unroll
                for (int c = 0; c < 4; c++)
                    async_cp16(src + (size_t)c * 64 * 1024, dst + c * 4096);
            }
        }
    };

    issueB(0, Bs + w * 512);
    issueB(1, Bs + 16384 + w * 512);

    float4v acc1[2][4], acc2[2][4], xr[2][4];
    #pragma unroll
    for (int i = 0; i < 2; i++)
        #pragma unroll
        for (int j = 0; j < 4; j++) {
            acc1[i][j] = (float4v){0.f, 0.f, 0.f, 0.f};   // proj accumulator
            acc2[i][j] = (float4v){0.f, 0.f, 0.f, 0.f};
        }

    #pragma unroll
    for (int t = 0; t < 36; ++t) {
        if (t == 35) asm volatile("s_waitcnt vmcnt(0)" ::: "memory");
        else         asm volatile("s_waitcnt vmcnt(4)" ::: "memory");
        __builtin_amdgcn_s_barrier();
        if (t + 2 < 36)
            issueB(t + 2, Bs + ((t + 2) % 3) * 16384 + w * 512);
        const u16* Bb = Bs + (t % 3) * 16384;

        if (t < 4) {
            // ---- proj tile t: acc1 += att-frag x wpT-tile ----
            __builtin_amdgcn_s_setprio(1);
            #pragma unroll
            for (int kk = 0; kk < 64; kk += 32) {
                const int slot = (((kk >> 3) + q) ^ sw) * 8;
                short8v bf[4];
                #pragma unroll
                for (int ni = 0; ni < 4; ni++)
                    bf[ni] = *(const short8v*)&Bb[(wn + ni * 16 + fm) * 64 + slot];
                #pragma unroll
                for (int mi = 0; mi < 2; mi++)
                    #pragma unroll
                    for (int ni = 0; ni < 4; ni++)
                        acc1[mi][ni] = __builtin_amdgcn_mfma_f32_16x16x32_bf16(
                            bf[ni], ar[t * 2 + (kk >> 5)][mi], acc1[mi][ni], 0, 0, 0);
            }
            __builtin_amdgcn_s_setprio(0);
            if (t == 3) {
                // ======== LN2 interlude ========
                float s[2] = {0.f, 0.f}, s2[2] = {0.f, 0.f};
                #pragma unroll
                for (int mi = 0; mi < 2; mi++)
                    #pragma unroll
                    for (int ni = 0; ni < 4; ni++) {
                        const int nb = wn + ni * 16 + q * 4;
                        const int row = m0 + wm + mi * 16 + fm;
                        float4 bv = *(const float4*)&bp[nb];
                        float4 xv = *(const float4*)(x + (size_t)row * 256 + nb);
                        #pragma unroll
                        for (int r = 0; r < 4; r++) {
                            float tv = acc1[mi][ni][r] + (&bv.x)[r] + (&xv.x)[r];
                            xr[mi][ni][r] = tv;
                            s[mi] += tv; s2[mi] += tv * tv;
                        }
                    }
                #pragma unroll
                for (int mi = 0; mi < 2; mi++) {
                    s[mi]  += __shfl_xor(s[mi], 16);  s[mi]  += __shfl_xor(s[mi], 32);
                    s2[mi] += __shfl_xor(s2[mi], 16); s2[mi] += __shfl_xor(s2[mi], 32);
                }
                if (q == 0) {
                    ps[wmi][0][fm][wni] = s[0];  ps[wmi][1][fm][wni] = s[1];
                    pq[wmi][0][fm][wni] = s2[0]; pq[wmi][1][fm][wni] = s2[1];
                }
                asm volatile("s_waitcnt lgkmcnt(0)" ::: "memory");
                __builtin_amdgcn_s_barrier();
                float mu[2], rs[2];
                #pragma unroll
                for (int mi = 0; mi < 2; mi++) {
                    float S  = ps[wmi][mi][fm][0] + ps[wmi][mi][fm][1]
                             + ps[wmi][mi][fm][2] + ps[wmi][mi][fm][3];
                    float SQ = pq[wmi][mi][fm][0] + pq[wmi][mi][fm][1]
                             + pq[wmi][mi][fm][2] + pq[wmi][mi][fm][3];
                    mu[mi] = S * 0.00390625f;
                    rs[mi] = rsqrtf(SQ * 0.00390625f - mu[mi] * mu[mi] + 1e-5f);
                }
                // h2 -> Ms (Hs) in swizzled A layout
                #pragma unroll
                for (int ni = 0; ni < 4; ni++) {
                    const int c2 = wn + ni * 16 + q * 4;
                    const int kcM = c2 >> 6, cc = c2 & 63;
                    float4 gv = *(const float4*)&g2[c2];
                    float4 bv = *(const float4*)&be2[c2];
                    #pragma unroll
                    for (int mi = 0; mi < 2; mi++) {
                        const int row = wm + mi * 16 + fm;
                        float h0 = (xr[mi][ni][0] - mu[mi]) * rs[mi] * gv.x + bv.x;
                        float h1 = (xr[mi][ni][1] - mu[mi]) * rs[mi] * gv.y + bv.y;
                        float h2v = (xr[mi][ni][2] - mu[mi]) * rs[mi] * gv.z + bv.z;
                        float h3 = (xr[mi][ni][3] - mu[mi]) * rs[mi] * gv.w + bv.w;
                        uint2 pp;
                        pp.x = (u32)f2b(h0) | ((u32)f2b(h1) << 16);
                        pp.y = (u32)f2b(h2v) | ((u32)f2b(h3) << 16);
                        *(uint2*)&Ms[kcM * 4096 + row * 64 +
                                     (((cc >> 3) ^ (row & 7)) * 8) + (cc & 7)] = pp;
                    }
                }
                asm volatile("s_waitcnt lgkmcnt(0)" ::: "memory");
                __builtin_amdgcn_s_barrier();
                // reload ar from Ms(Hs): ar[kcn][mi] = h2[row][kcn*32 + q*8]
                #pragma unroll
                for (int kcn = 0; kcn < 8; kcn++) {
                    const int kcq = kcn >> 1, kk = (kcn & 1) * 32;
                    const int slot = (((kk >> 3) + q) ^ sw) * 8;
                    #pragma unroll
                    for (int mi = 0; mi < 2; mi++)
                        ar[kcn][mi] = *(const short8v*)&Ms[kcq * 4096 +
                                        (wm + mi * 16 + fm) * 64 + slot];
                }
            }
        } else {
            const int tt = t - 4;
            const int nch = tt >> 3, ph = (tt >> 2) & 1, kc = tt & 3;
            if (ph == 0) {
                if (kc == 0) {
                    #pragma unroll
                    for (int i = 0; i < 2; i++)
                        #pragma unroll
                        for (int j = 0; j < 4; j++) acc1[i][j] = (float4v){0.f, 0.f, 0.f, 0.f};
                }
                __builtin_amdgcn_s_setprio(1);
                #pragma unroll
                for (int kk = 0; kk < 64; kk += 32) {
                    const int slot = (((kk >> 3) + q) ^ sw) * 8;
                    short8v bf[4];
                    #pragma unroll
                    for (int ni = 0; ni < 4; ni++)
                        bf[ni] = *(const short8v*)&Bb[(wn + ni * 16 + fm) * 64 + slot];
                    #pragma unroll
                    for (int mi = 0; mi < 2; mi++)
                        #pragma unroll
                        for (int ni = 0; ni < 4; ni++)
                            acc1[mi][ni] = __builtin_amdgcn_mfma_f32_16x16x32_bf16(
                                bf[ni], ar[kc * 2 + (kk >> 5)][mi], acc1[mi][ni], 0, 0, 0);
                }
                __builtin_amdgcn_s_setprio(0);
                if (kc == 3) {
                    // bias + relu -> Ms (swizzled A layout for gemm2)
                    #pragma unroll
                    for (int ni = 0; ni < 4; ni++) {
                        const int c2 = wn + ni * 16 + q * 4;       // 0..255
                        const int kcM = c2 >> 6, cc = c2 & 63;
                        float4 bv = *(const float4*)&b1[nch * 256 + c2];
                        #pragma unroll
                        for (int mi = 0; mi < 2; mi++) {
                            const int row = wm + mi * 16 + fm;
                            float v0 = fmaxf(acc1[mi][ni][0] + bv.x, 0.f);
                            float v1 = fmaxf(acc1[mi][ni][1] + bv.y, 0.f);
                            float v2 = fmaxf(acc1[mi][ni][2] + bv.z, 0.f);
                            float v3 = fmaxf(acc1[mi][ni][3] + bv.w, 0.f);
                            uint2 pp;
                            pp.x = (u32)f2b(v0) | ((u32)f2b(v1) << 16);
                            pp.y = (u32)f2b(v2) | ((u32)f2b(v3) << 16);
                            *(uint2*)&Ms[kcM * 4096 + row * 64 +
                                         (((cc >> 3) ^ (row & 7)) * 8) + (cc & 7)] = pp;
                        }
                    }
                    asm volatile("s_waitcnt lgkmcnt(0)" ::: "memory");
                }
            } else {
                const u16* Ab = Ms + kc * 4096;
                __builtin_amdgcn_s_setprio(1);
                #pragma unroll
                for (int kk = 0; kk < 64; kk += 32) {
                    const int slot = (((kk >> 3) + q) ^ sw) * 8;
                    short8v af[2], bf[4];
                    #pragma unroll
                    for (int mi = 0; mi < 2; mi++)
                        af[mi] = *(const short8v*)&Ab[(wm + mi * 16 + fm) * 64 + slot];
                    #pragma unroll
                    for (int ni = 0; ni < 4; ni++)
                        bf[ni] = *(const short8v*)&Bb[(wn + ni * 16 + fm) * 64 + slot];
                    #pragma unroll
                    for (int mi = 0; mi < 2; mi++)
                        #pragma unroll
                        for (int ni = 0; ni < 4; ni++)
                            acc2[mi][ni] = __builtin_amdgcn_mfma_f32_16x16x32_bf16(
                                bf[ni], af[mi], acc2[mi][ni], 0, 0, 0);
                }
                __builtin_amdgcn_s_setprio(0);
            }
        }
    }

    // ---- epilogue: out = xr (= x + att@wp + bp) + acc2 + b2, fp32 stores ---
    #pragma unroll
    for (int mi = 0; mi < 2; mi++) {
        const int row = m0 + wm + mi * 16 + fm;
        #pragma unroll
        for (int ni = 0; ni < 4; ni++) {
            const int nb = wn + ni * 16 + q * 4;
            size_t idx = (size_t)row * 256 + nb;
            float4 bv = *(const float4*)&b2[nb];
            float v0 = acc2[mi][ni][0] + bv.x + xr[mi][ni][0];
            float v1 = acc2[mi][ni][1] + bv.y + xr[mi][ni][1];
            float v2 = acc2[mi][ni][2] + bv.z + xr[mi][ni][2];
            float v3 = acc2[mi][ni][3] + bv.w + xr[mi][ni][3];
            *(float4*)&out[idx] = (float4){v0, v1, v2, v3};
        }
    }
}

// ---------------- MFMA flash attention: dbuf K/V, 1 barrier/tile ------------
__global__ __launch_bounds__(256) void attn_mfma(const u16* __restrict__ qk,
                                                 const u16* __restrict__ vtg,
                                                 u16* __restrict__ att) {
    const int T = 1024;
    int jj = (blockIdx.x + (blockIdx.y >> 3)) & 7;
    int b = blockIdx.y >> 3, hh = blockIdx.y & 7;
    int tid = threadIdx.x;
    int lane = tid & 63, w = tid >> 6;
    int fm = lane & 15, q = lane >> 4;

    __shared__ __align__(16) u16 Ks[2][64][72];
    __shared__ __align__(16) u16 Vt[2][32][72];
    __shared__ __align__(16) u16 Pl[4][16][72];

    size_t base = (size_t)b * T * 512;
    const u16* kb = qk + base + 256 + hh * 32;
    const u16* vt = vtg + (size_t)((b * 8 + hh) * 32) * 1024;
    const int krow = tid >> 2, kcol = (tid & 3) * 8;
    const int vd = tid >> 3, vs = (tid & 7) * 8;

    int qa0 = jj * 64, qb0 = (15 - jj) * 64;
    int tqa = qa0 + w * 16 + fm, tqb = qb0 + w * 16 + fm;
    short8v qfa = *(const short8v*)(qk + base + (size_t)tqa * 512 + hh * 32 + q * 8);
    short8v qfb = *(const short8v*)(qk + base + (size_t)tqb * 512 + hh * 32 + q * 8);
    float4v oa0 = {0.f, 0.f, 0.f, 0.f}, oa1 = {0.f, 0.f, 0.f, 0.f};
    float4v ob0 = {0.f, 0.f, 0.f, 0.f}, ob1 = {0.f, 0.f, 0.f, 0.f};
    float la = 0.f, lb = 0.f;
    int wqa = qa0 + w * 16, wqb = qb0 + w * 16;
    int nIter = 16 - jj;

    uint4 kreg = *(const uint4*)(kb + (size_t)krow * 512 + kcol);
    uint4 vreg = *(const uint4*)(vt + (size_t)vd * 1024 + vs);

    for (int it = 0; it < nIter; ++it) {
        int s0 = it << 6;
        const int cb = it & 1;
        // write tile it into buf cb (reads of cb ended 2 barriers ago),
        // prefetch tile it+1 into regs, ONE barrier, read frags from cb.
        *(uint4*)&Ks[cb][krow][kcol] = kreg;
        *(uint4*)&Vt[cb][vd][vs] = vreg;
        if (it + 1 < nIter) {
            int ns0 = s0 + 64;
            kreg = *(const uint4*)(kb + (size_t)(ns0 + krow) * 512 + kcol);
            vreg = *(const uint4*)(vt + (size_t)vd * 1024 + ns0 + vs);
        }
        asm volatile("s_waitcnt lgkmcnt(0)" ::: "memory");
        __builtin_amdgcn_s_barrier();
        short8v kf0 = *(const short8v*)&Ks[cb][fm][q * 8];
        short8v kf1 = *(const short8v*)&Ks[cb][16 + fm][q * 8];
        short8v kf2 = *(const short8v*)&Ks[cb][32 + fm][q * 8];
        short8v kf3 = *(const short8v*)&Ks[cb][48 + fm][q * 8];
        short8v vf00 = *(const short8v*)&Vt[cb][fm][q * 8];
        short8v vf01 = *(const short8v*)&Vt[cb][fm][32 + q * 8];
        short8v vf10 = *(const short8v*)&Vt[cb][16 + fm][q * 8];
        short8v vf11 = *(const short8v*)&Vt[cb][16 + fm][32 + q * 8];
        float4v z = {0.f, 0.f, 0.f, 0.f};

        #pragma unroll
        for (int t2 = 0; t2 < 2; t2++) {       // t2=0: tile b (large), 1: tile a
            int wq0 = t2 ? wqa : wqb;
            if (s0 >= wq0 + 16) continue;      // wave-uniform causal skip
            int tq = t2 ? tqa : tqb;
            short8v qf = t2 ? qfa : qfb;
            __builtin_amdgcn_s_setprio(1);
            float4v s_0 = __builtin_amdgcn_mfma_f32_16x16x32_bf16(kf0, qf, z, 0, 0, 0);
            float4v s_1 = __builtin_amdgcn_mfma_f32_16x16x32_bf16(kf1, qf, z, 0, 0, 0);
            float4v s_2 = __builtin_amdgcn_mfma_f32_16x16x32_bf16(kf2, qf, z, 0, 0, 0);
            float4v s_3 = __builtin_amdgcn_mfma_f32_16x16x32_bf16(kf3, qf, z, 0, 0, 0);
            __builtin_amdgcn_s_setprio(0);
            float p[16];
            #pragma unroll
            for (int r = 0; r < 4; r++) {
                p[r] = exp2f(s_0[r]); p[4 + r] = exp2f(s_1[r]);
                p[8 + r] = exp2f(s_2[r]); p[12 + r] = exp2f(s_3[r]);
            }
            if (s0 + 63 > wq0) {               // diagonal region: causal mask
                int sb = s0 + q * 4;
                #pragma unroll
                for (int c = 0; c < 4; c++)
                    #pragma unroll
                    for (int r = 0; r < 4; r++)
                        if (sb + c * 16 + r > tq) p[c * 4 + r] = 0.f;
            }
            float rsum = 0.f;
            #pragma unroll
            for (int i = 0; i < 16; i++) rsum += p[i];
            rsum += __shfl_xor(rsum, 16);
            rsum += __shfl_xor(rsum, 32);
            if (t2) la += rsum; else lb += rsum;

            #pragma unroll
            for (int c = 0; c < 4; c++) {
                uint2 pp;
                pp.x = pk2_rtz(p[c * 4 + 0], p[c * 4 + 1]);
                pp.y = pk2_rtz(p[c * 4 + 2], p[c * 4 + 3]);
                *(uint2*)&Pl[w][fm][c * 16 + q * 4] = pp;   // wave-internal
            }
            short8v pf0 = *(const short8v*)&Pl[w][fm][q * 8];
            short8v pf1 = *(const short8v*)&Pl[w][fm][32 + q * 8];
            __builtin_amdgcn_s_setprio(1);
            if (t2) {
                oa0 = __builtin_amdgcn_mfma_f32_16x16x32_bf16(vf00, pf0, oa0, 0, 0, 0);
                oa0 = __builtin_amdgcn_mfma_f32_16x16x32_bf16(vf01, pf1, oa0, 0, 0, 0);
                oa1 = __builtin_amdgcn_mfma_f32_16x16x32_bf16(vf10, pf0, oa1, 0, 0, 0);
                oa1 = __builtin_amdgcn_mfma_f32_16x16x32_bf16(vf11, pf1, oa1, 0, 0, 0);
            } else {
                ob0 = __builtin_amdgcn_mfma_f32_16x16x32_bf16(vf00, pf0, ob0, 0, 0, 0);
                ob0 = __builtin_amdgcn_mfma_f32_16x16x32_bf16(vf01, pf1, ob0, 0, 0, 0);
                ob1 = __builtin_amdgcn_mfma_f32_16x16x32_bf16(vf10, pf0, ob1, 0, 0, 0);
                ob1 = __builtin_amdgcn_mfma_f32_16x16x32_bf16(vf11, pf1, ob1, 0, 0, 0);
            }
            __builtin_amdgcn_s_setprio(0);
        }
    }

    #pragma unroll
    for (int t2 = 0; t2 < 2; t2++) {
        float inv = 1.f / (t2 ? la : lb);
        float4v o0 = t2 ? oa0 : ob0, o1 = t2 ? oa1 : ob1;
        int tq = t2 ? tqa : tqb;
        uint2 r0, r1;
        r0.x = (u32)f2b(o0[0] * inv) | ((u32)f2b(o0[1] * inv) << 16);
        r0.y = (u32)f2b(o0[2] * inv) | ((u32)f2b(o0[3] * inv) << 16);
        r1.x = (u32)f2b(o1[0] * inv) | ((u32)f2b(o1[1] * inv) << 16);
        r1.y = (u32)f2b(o1[2] * inv) | ((u32)f2b(o1[3] * inv) << 16);
        size_t o = (size_t)(b * T + tq) * 256 + hh * 32;
        *(uint2*)(att + o + q * 4) = r0;
        *(uint2*)(att + o + 16 + q * 4) = r1;
    }
}

// ---------------- launch ----------------
extern "C" void kernel_launch(void* const* d_in, const int* in_sizes, int n_in,
                              void* d_out, int out_size, void* d_ws, size_t ws_size,
                              hipStream_t stream) {
    const int BT = 16 * 1024;
    const float* x      = (const float*)d_in[0];
    const float* wq     = (const float*)d_in[1];
    const float* wk     = (const float*)d_in[2];
    const float* wv     = (const float*)d_in[3];
    const float* w_proj = (const float*)d_in[4];
    const float* b_proj = (const float*)d_in[5];
    const float* w1     = (const float*)d_in[6];
    const float* b1     = (const float*)d_in[7];
    const float* w2     = (const float*)d_in[8];
    const float* b2     = (const float*)d_in[9];
    const float* ln1_g  = (const float*)d_in[10];
    const float* ln1_b  = (const float*)d_in[11];
    const float* ln2_g  = (const float*)d_in[12];
    const float* ln2_b  = (const float*)d_in[13];

    // Workspace: [8M,16M) hbuf h->att | [16M,32M) qk | [32M,48M) vtg
    //            [48M...) packed weights (1.5M)
    char* ws = (char*)d_ws;
    const size_t MB = 1024 * 1024;
    u16*  hbuf  = (u16*)(ws + 8 * MB);
    u16*  qk    = (u16*)(ws + 16 * MB);
    u16*  vtg   = (u16*)(ws + 32 * MB);
    u16*  wqkvT = (u16*)(ws + 48 * MB);
    u16*  wpT   = (u16*)(ws + 48 * MB + 0x60000);
    u16*  w1T   = (u16*)(ws + 48 * MB + 0x80000);
    u16*  w2T   = (u16*)(ws + 48 * MB + 0x100000);

    prep_ln1<<<5008, 256, 0, stream>>>(wq, wk, wv, w_proj, w1, w2, x, ln1_g, ln1_b,
                                       wqkvT, wpT, w1T, w2T, hbuf);
    // qk | vtg = h @ [Wq'|Wk|Wv]  [counted-vmcnt dbuf]
    gemm128<false, false, true><<<dim3(128, 6), 256, 0, stream>>>(
        hbuf, wqkvT, nullptr, qk, vtg, BT, 512, 256);
    // att = flash attention (writes over h)  [dbuf K/V, 1 barrier/tile]
    attn_mfma<<<dim3(8, 128), 256, 0, stream>>>(qk, vtg, hbuf);
    // out = x2 + relu(LN2(x + att@wp + bp) @ w1 + b1) @ w2 + b2  [one kernel]
    tail_fused<<<256, 512, 0, stream>>>(hbuf, wpT, b_proj, x, ln2_g, ln2_b,
                                        w1T, b1, w2T, b2, (float*)d_out);
}